// Round 3
// baseline (594.882 us; speedup 1.0000x reference)
//
#include <hip/hip_runtime.h>
#include <hip/hip_bf16.h>

#define N_NODES 25000
#define N_EDGES 320000
#define F 64            // IN_FEAT == OUT_FEAT
#define H 5             // heads
#define R 20            // relations
#define B 10            // bases
#define TBL (R * 2 * F * H)   // 20*128*5 = 12800 floats

// ---- dual-dtype loaders (flag is wave-uniform; if/else prevents speculative OOB loads)
__device__ __forceinline__ float ldf(const void* p, int f32, int i) {
    if (f32) return ((const float*)p)[i];
    else     return __bfloat162float(((const __hip_bfloat16*)p)[i]);
}
__device__ __forceinline__ int ldi(const void* p, int i64, int i) {
    if (i64) return ((const int*)p)[2 * i];   // little-endian low word of int64 (values < 2^31)
    else     return ((const int*)p)[i];
}

// ---------------- Kernel 0: probe input dtypes, write flags[0]=f32?, flags[1]=i64?
__global__ void k_probe(const unsigned int* __restrict__ feat_raw,
                        const unsigned int* __restrict__ src_raw,
                        int* __restrict__ flags) {
    __shared__ int sSane, sZero;
    const int tid = threadIdx.x;
    if (tid == 0) { sSane = 0; sZero = 0; }
    __syncthreads();
    int sane = 0, zero = 0;
    for (int i = tid; i < 4096; i += 256) {
        unsigned w = feat_raw[i];
        unsigned e = (w >> 7) & 0xFF;          // bf16 exponent of the LOW half
        if (e >= 110 && e <= 140) sane++;      // clustered ~127 iff packed bf16
        if (src_raw[2 * i + 1] == 0) zero++;   // odd words all zero iff int64
    }
    atomicAdd(&sSane, sane);
    atomicAdd(&sZero, zero);
    __syncthreads();
    if (tid == 0) {
        flags[0] = (sSane < 2048) ? 1 : 0;     // fp32 floats
        flags[1] = (sZero > 2048) ? 1 : 0;     // int64 indices
    }
}

// ---------------- Kernel A: attn_fcs[r,f2,h] = sum_b w_comp[r,b] * aw[b,f2,h]
__global__ void k_attn_tbl(const void* __restrict__ wc,
                           const void* __restrict__ aw,
                           float* __restrict__ tbl,
                           const int* __restrict__ flags) {
    const int f32 = flags[0];
    int idx = blockIdx.x * blockDim.x + threadIdx.x;
    if (idx >= TBL) return;
    int r = idx / (2 * F * H);
    int rem = idx % (2 * F * H);     // f2*H + h
    float acc = 0.f;
#pragma unroll
    for (int b = 0; b < B; ++b)
        acc += ldf(wc, f32, r * B + b) * ldf(aw, f32, b * (2 * F * H) + rem);
    tbl[idx] = acc;
}

// ---------------- Kernel P: z = feat@fc_w ; hacc = feat@self_fc_w (init)
// 384 threads = 6 waves. Waves 0..4 own the 320 columns of self_fc_w,
// wave 5 owns the 64 columns of fc_w. Weight column lives in 64 VGPRs.
// feat row broadcast via __shfl (register-only, race-free).
__global__ __launch_bounds__(384) void k_proj(const void* __restrict__ feat,
                                              const void* __restrict__ fcw,
                                              const void* __restrict__ sfw,
                                              float* __restrict__ z,
                                              float* __restrict__ hacc,
                                              const int* __restrict__ flags,
                                              int n) {
    const int f32 = flags[0];
    const int tid = threadIdx.x;
    const int wave = tid >> 6;
    const int lane = tid & 63;

    float w[F];
    if (wave < 5) {
#pragma unroll
        for (int k = 0; k < F; ++k) w[k] = ldf(sfw, f32, k * (H * F) + tid);
    } else {
#pragma unroll
        for (int k = 0; k < F; ++k) w[k] = ldf(fcw, f32, k * F + lane);
    }

    for (int row = blockIdx.x; row < n; row += gridDim.x) {
        const float v = ldf(feat, f32, row * F + lane);
        float acc = 0.f;
#pragma unroll
        for (int k = 0; k < F; ++k) acc += __shfl(v, k, 64) * w[k];
        if (wave < 5) hacc[row * (H * F) + tid] = acc;
        else          z[row * F + lane] = acc;
    }
}

// ---------------- Kernel D: per-edge attention + scatter into hacc
__global__ __launch_bounds__(256) void k_edge(const void* __restrict__ src,
                                              const void* __restrict__ dst,
                                              const void* __restrict__ et,
                                              const float* __restrict__ z,
                                              const float* __restrict__ tbl,
                                              float* __restrict__ hacc,
                                              const int* __restrict__ flags,
                                              int ne) {
    __shared__ float sw[TBL];   // 51.2 KB: full relation table
    const int i64 = flags[1];
    const int tid = threadIdx.x;
    for (int i = tid; i < TBL; i += 256) sw[i] = tbl[i];
    __syncthreads();

    const int lane = tid & 63;
    const int wid = (blockIdx.x << 2) | (tid >> 6);
    const int nw = gridDim.x << 2;

    for (int e = wid; e < ne; e += nw) {
        const int s = ldi(src, i64, e);
        const int d = ldi(dst, i64, e);
        const int r = ldi(et, i64, e);
        const float zs = z[s * F + lane];
        const float zd = z[d * F + lane];
        const float* W = &sw[r * (2 * F * H)];

        float att[H];
#pragma unroll
        for (int h = 0; h < H; ++h) {
            float p = zs * W[lane * H + h] + zd * W[(F + lane) * H + h];
#pragma unroll
            for (int off = 32; off; off >>= 1) p += __shfl_xor(p, off, 64);
            att[h] = p > 0.f ? p : 0.01f * p;
        }

        float* outp = &hacc[d * (H * F) + lane];
#pragma unroll
        for (int h = 0; h < H; ++h)
            atomicAdd(outp + h * F, att[h] * zs);
    }
}

// ---------------- Kernel E: fp32 accumulator -> output (dtype matches inputs)
__global__ void k_cast(const float* __restrict__ hacc, void* __restrict__ out,
                       const int* __restrict__ flags, int n) {
    const int f32 = flags[0];
    int i = (blockIdx.x * blockDim.x + threadIdx.x) * 4;
    if (i >= n) return;
    float4 v = *(const float4*)(hacc + i);
    if (f32) {
        *(float4*)((float*)out + i) = v;
    } else {
        __hip_bfloat16* o = (__hip_bfloat16*)out;
        __hip_bfloat162 a, b;
        a.x = __float2bfloat16(v.x); a.y = __float2bfloat16(v.y);
        b.x = __float2bfloat16(v.z); b.y = __float2bfloat16(v.w);
        *(__hip_bfloat162*)(o + i) = a;
        *(__hip_bfloat162*)(o + i + 2) = b;
    }
}

extern "C" void kernel_launch(void* const* d_in, const int* in_sizes, int n_in,
                              void* d_out, int out_size, void* d_ws, size_t ws_size,
                              hipStream_t stream) {
    const void* feat = d_in[0];
    const void* src  = d_in[1];
    const void* dst  = d_in[2];
    const void* et   = d_in[3];
    const void* fcw  = d_in[4];
    const void* sfw  = d_in[5];
    const void* aw   = d_in[6];
    const void* wc   = d_in[7];

    // workspace layout (fp32): [tbl 16384][z 25000*64][hacc 25000*320][flags]
    float* tbl  = (float*)d_ws;
    float* z    = tbl + 16384;
    float* hacc = z + (size_t)N_NODES * F;
    int* flags  = (int*)(hacc + (size_t)N_NODES * H * F);

    k_probe<<<1, 256, 0, stream>>>((const unsigned int*)feat, (const unsigned int*)src, flags);
    k_attn_tbl<<<(TBL + 255) / 256, 256, 0, stream>>>(wc, aw, tbl, flags);
    k_proj<<<800, 384, 0, stream>>>(feat, fcw, sfw, z, hacc, flags, N_NODES);
    k_edge<<<1280, 256, 0, stream>>>(src, dst, et, z, tbl, hacc, flags, N_EDGES);
    const int ncast = N_NODES * H * F;
    k_cast<<<(ncast / 4 + 255) / 256, 256, 0, stream>>>(hacc, d_out, flags, ncast);
}

// Round 4
// 463.643 us; speedup vs baseline: 1.2831x; 1.2831x over previous
//
#include <hip/hip_runtime.h>
#include <hip/hip_bf16.h>

#define N_NODES 25000
#define N_EDGES 320000
#define F 64            // IN_FEAT == OUT_FEAT
#define H 5             // heads
#define R 20            // relations
#define B 10            // bases
#define TBL (R * 2 * F * H)   // 12800 floats
#define HF (H * F)            // 320

// ---- dual-dtype loaders (flag is uniform; if/else prevents speculative OOB loads)
__device__ __forceinline__ float ldf(const void* p, int f32, int i) {
    if (f32) return ((const float*)p)[i];
    else     return __bfloat162float(((const __hip_bfloat16*)p)[i]);
}
__device__ __forceinline__ int ldi(const void* p, int i64, int i) {
    if (i64) return ((const int*)p)[2 * i];   // LE low word of int64
    else     return ((const int*)p)[i];
}

// ---------------- K0: probe input dtypes -> flags[0]=f32?, flags[1]=i64?
__global__ void k_probe(const unsigned int* __restrict__ feat_raw,
                        const unsigned int* __restrict__ src_raw,
                        int* __restrict__ flags) {
    __shared__ int sSane, sZero;
    const int tid = threadIdx.x;
    if (tid == 0) { sSane = 0; sZero = 0; }
    __syncthreads();
    int sane = 0, zero = 0;
    for (int i = tid; i < 4096; i += 256) {
        unsigned w = feat_raw[i];
        unsigned e = (w >> 7) & 0xFF;
        if (e >= 110 && e <= 140) sane++;      // clustered iff packed bf16
        if (src_raw[2 * i + 1] == 0) zero++;   // odd words zero iff int64
    }
    atomicAdd(&sSane, sane);
    atomicAdd(&sZero, zero);
    __syncthreads();
    if (tid == 0) {
        flags[0] = (sSane < 2048) ? 1 : 0;
        flags[1] = (sZero > 2048) ? 1 : 0;
    }
}

// ---------------- K1: compose attention table + zero the degree histogram
__global__ void k_prep(const void* __restrict__ wc, const void* __restrict__ aw,
                       float* __restrict__ tbl, int* __restrict__ deg,
                       const int* __restrict__ flags) {
    const int f32 = flags[0];
    int idx = blockIdx.x * blockDim.x + threadIdx.x;
    if (idx < N_NODES) deg[idx] = 0;
    if (idx < TBL) {
        int r = idx / (2 * F * H);
        int rem = idx % (2 * F * H);
        float acc = 0.f;
#pragma unroll
        for (int b = 0; b < B; ++b)
            acc += ldf(wc, f32, r * B + b) * ldf(aw, f32, b * (2 * F * H) + rem);
        tbl[idx] = acc;
    }
}

// ---------------- K2: z = feat@fc_w (fp32) ; selfz = feat@self_fc_w (bf16)
__global__ __launch_bounds__(384) void k_proj(const void* __restrict__ feat,
                                              const void* __restrict__ fcw,
                                              const void* __restrict__ sfw,
                                              float* __restrict__ z,
                                              __hip_bfloat16* __restrict__ selfzb,
                                              const int* __restrict__ flags,
                                              int n) {
    const int f32 = flags[0];
    const int tid = threadIdx.x;
    const int wave = tid >> 6;
    const int lane = tid & 63;

    float w[F];
    if (wave < 5) {
#pragma unroll
        for (int k = 0; k < F; ++k) w[k] = ldf(sfw, f32, k * HF + tid);
    } else {
#pragma unroll
        for (int k = 0; k < F; ++k) w[k] = ldf(fcw, f32, k * F + lane);
    }

    for (int row = blockIdx.x; row < n; row += gridDim.x) {
        const float v = ldf(feat, f32, row * F + lane);
        float acc = 0.f;
#pragma unroll
        for (int k = 0; k < F; ++k) acc += __shfl(v, k, 64) * w[k];
        if (wave < 5) selfzb[row * HF + tid] = __float2bfloat16(acc);
        else          z[row * F + lane] = acc;
    }
}

// ---------------- K3: degree histogram over dst
__global__ void k_hist(const void* __restrict__ dst, int* __restrict__ deg,
                       const int* __restrict__ flags, int ne) {
    const int i64 = flags[1];
    int e = blockIdx.x * blockDim.x + threadIdx.x;
    if (e >= ne) return;
    atomicAdd(&deg[ldi(dst, i64, e)], 1);
}

// ---------------- K4: single-block exclusive scan -> rowptr, cursor
__global__ __launch_bounds__(1024) void k_scan(const int* __restrict__ deg,
                                               int* __restrict__ rowptr,
                                               int* __restrict__ cursor) {
    __shared__ int tot[1024];
    const int t = threadIdx.x;
    const int base = t * 25;                   // 1024*25 = 25600 >= 25000
    int s = 0;
#pragma unroll
    for (int i = 0; i < 25; ++i) {
        int idx = base + i;
        if (idx < N_NODES) s += deg[idx];
    }
    tot[t] = s;
    __syncthreads();
    for (int off = 1; off < 1024; off <<= 1) {
        int v = (t >= off) ? tot[t - off] : 0;
        __syncthreads();
        tot[t] += v;
        __syncthreads();
    }
    int run = (t > 0) ? tot[t - 1] : 0;        // exclusive base for this chunk
#pragma unroll
    for (int i = 0; i < 25; ++i) {
        int idx = base + i;
        if (idx < N_NODES) {
            rowptr[idx] = run;
            cursor[idx] = run;
            run += deg[idx];
        }
    }
    if (t == 1023) rowptr[N_NODES] = tot[1023];
}

// ---------------- K5: scatter edges into CSR order, packed (rel<<16)|src
__global__ void k_scatter(const void* __restrict__ src, const void* __restrict__ dst,
                          const void* __restrict__ et, int* __restrict__ cursor,
                          unsigned* __restrict__ perm, const int* __restrict__ flags,
                          int ne) {
    const int i64 = flags[1];
    int e = blockIdx.x * blockDim.x + threadIdx.x;
    if (e >= ne) return;
    int d = ldi(dst, i64, e);
    int s = ldi(src, i64, e);
    int r = ldi(et, i64, e);
    int pos = atomicAdd(&cursor[d], 1);
    perm[pos] = ((unsigned)r << 16) | (unsigned)s;   // s < 25000 < 2^16
}

// ---------------- K6: one wave per dst — attention + aggregate + self + cast
__global__ __launch_bounds__(512) void k_agg(const float* __restrict__ z,
                                             const float* __restrict__ tbl,
                                             const __hip_bfloat16* __restrict__ selfzb,
                                             const int* __restrict__ rowptr,
                                             const unsigned* __restrict__ perm,
                                             void* __restrict__ out,
                                             const int* __restrict__ flags) {
    __shared__ float sw[TBL];   // 51.2 KB -> 3 blocks/CU, 24 waves/CU
    const int tid = threadIdx.x;
    for (int i = tid; i < TBL; i += 512) sw[i] = tbl[i];
    __syncthreads();

    const int f32 = flags[0];
    const int lane = tid & 63;
    const int l5 = lane * H;
    const int d = blockIdx.x * 8 + (tid >> 6);     // 3125*8 = 25000 exactly
    if (d >= N_NODES) return;

    const int beg = rowptr[d];
    const int end = rowptr[d + 1];
    const float zd = z[d * F + lane];

    float acc[H] = {0.f, 0.f, 0.f, 0.f, 0.f};
    for (int e = beg; e < end; ++e) {
        const unsigned pk = perm[e];
        const int s = (int)(pk & 0xFFFFu);
        const float* W = &sw[(pk >> 16) * (2 * F * H)];
        const float zs = z[s * F + lane];
#pragma unroll
        for (int h = 0; h < H; ++h) {
            float p = zs * W[l5 + h] + zd * W[l5 + h + F * H];
#pragma unroll
            for (int off = 32; off; off >>= 1) p += __shfl_xor(p, off, 64);
            float a = p > 0.f ? p : 0.01f * p;
            acc[h] += a * zs;
        }
    }

    const int ob = d * HF + lane;
    if (f32) {
        float* o = (float*)out;
#pragma unroll
        for (int h = 0; h < H; ++h)
            o[ob + h * F] = acc[h] + __bfloat162float(selfzb[ob + h * F]);
    } else {
        __hip_bfloat16* o = (__hip_bfloat16*)out;
#pragma unroll
        for (int h = 0; h < H; ++h)
            o[ob + h * F] = __float2bfloat16(acc[h] + __bfloat162float(selfzb[ob + h * F]));
    }
}

extern "C" void kernel_launch(void* const* d_in, const int* in_sizes, int n_in,
                              void* d_out, int out_size, void* d_ws, size_t ws_size,
                              hipStream_t stream) {
    const void* feat = d_in[0];
    const void* src  = d_in[1];
    const void* dst  = d_in[2];
    const void* et   = d_in[3];
    const void* fcw  = d_in[4];
    const void* sfw  = d_in[5];
    const void* aw   = d_in[6];
    const void* wc   = d_in[7];

    // ws layout (~24.1 MB): tbl | z(fp32) | selfz(bf16) | flags | deg | rowptr | cursor | perm
    float* tbl = (float*)d_ws;
    float* z   = tbl + TBL;
    __hip_bfloat16* selfzb = (__hip_bfloat16*)(z + (size_t)N_NODES * F);
    int* flags  = (int*)(selfzb + (size_t)N_NODES * HF);
    int* deg    = flags + 4;
    int* rowptr = deg + N_NODES;
    int* cursor = rowptr + N_NODES + 1;
    unsigned* perm = (unsigned*)(cursor + N_NODES);

    k_probe<<<1, 256, 0, stream>>>((const unsigned int*)feat, (const unsigned int*)src, flags);
    k_prep<<<(N_NODES + 255) / 256, 256, 0, stream>>>(wc, aw, tbl, deg, flags);
    k_proj<<<800, 384, 0, stream>>>(feat, fcw, sfw, z, selfzb, flags, N_NODES);
    k_hist<<<(N_EDGES + 255) / 256, 256, 0, stream>>>(dst, deg, flags, N_EDGES);
    k_scan<<<1, 1024, 0, stream>>>(deg, rowptr, cursor);
    k_scatter<<<(N_EDGES + 255) / 256, 256, 0, stream>>>(src, dst, et, cursor, perm, flags, N_EDGES);
    k_agg<<<(N_NODES + 7) / 8, 512, 0, stream>>>(z, tbl, selfzb, rowptr, perm, d_out, flags);
}

// Round 5
// 242.294 us; speedup vs baseline: 2.4552x; 1.9136x over previous
//
#include <hip/hip_runtime.h>
#include <hip/hip_bf16.h>

#define N_NODES 25000
#define N_EDGES 320000
#define F 64
#define H 5
#define R 20
#define B 10
#define HF 320            // H*F (selfz cols)
#define NP1 384           // P row stride: [selfz 0..319 | z 320..383]
#define NA 320            // a row stride: c = r*16 + part*8 + h  (h<5 valid)
#define MPAD 25008        // 1563*16 rows (padded M)

typedef __attribute__((ext_vector_type(8))) short short8;
typedef __attribute__((ext_vector_type(4))) float float4v;

// ---- dual-dtype loaders (uniform flag; if/else avoids speculative OOB)
__device__ __forceinline__ float ldf(const void* p, int f32, int i) {
    if (f32) return ((const float*)p)[i];
    else     return __bfloat162float(((const __hip_bfloat16*)p)[i]);
}
__device__ __forceinline__ int ldi(const void* p, int i64, int i) {
    if (i64) return ((const int*)p)[2 * i];
    else     return ((const int*)p)[i];
}
__device__ __forceinline__ float b2f(unsigned short u) {
    union { unsigned u32; float f; } v; v.u32 = ((unsigned)u) << 16; return v.f;
}

// ---------------- K0: probe input dtypes -> flags[0]=f32?, flags[1]=i64?
__global__ void k_probe(const unsigned int* __restrict__ feat_raw,
                        const unsigned int* __restrict__ src_raw,
                        int* __restrict__ flags) {
    __shared__ int sSane, sZero;
    const int tid = threadIdx.x;
    if (tid == 0) { sSane = 0; sZero = 0; }
    __syncthreads();
    int sane = 0, zero = 0;
    for (int i = tid; i < 4096; i += 256) {
        unsigned w = feat_raw[i];
        unsigned e = (w >> 7) & 0xFF;
        if (e >= 110 && e <= 140) sane++;
        if (src_raw[2 * i + 1] == 0) zero++;
    }
    atomicAdd(&sSane, sane);
    atomicAdd(&sZero, zero);
    __syncthreads();
    if (tid == 0) {
        flags[0] = (sSane < 2048) ? 1 : 0;
        flags[1] = (sZero > 2048) ? 1 : 0;
    }
}

// ---------------- K1: build packed weights + zero deg + (f32) convert feat
// Wpack: B-fragment order for GEMM1, Wpack[((t*2+q)*64+lane)*8+j] =
//        W[k=(q?32:0)+8*(lane>>4)+j][c=t*16+(lane&15)], W=[self_fc_w|fc_w], t<24
// W2pack: same order for GEMM2, W2[k][c], c=r*16+part*8+h (h<5 else 0), t<20
__global__ void k_setup(const void* __restrict__ feat, const void* __restrict__ fcw,
                        const void* __restrict__ sfw, const void* __restrict__ aw,
                        const void* __restrict__ wc,
                        __hip_bfloat16* __restrict__ Wpack,
                        __hip_bfloat16* __restrict__ W2pack,
                        __hip_bfloat16* __restrict__ featb,
                        int* __restrict__ deg, const int* __restrict__ flags) {
    const int f32 = flags[0];
    const int idx = blockIdx.x * blockDim.x + threadIdx.x;
    if (idx < N_NODES) deg[idx] = 0;
    if (idx < 24576) {
        int j = idx & 7, lane = (idx >> 3) & 63, fq = idx >> 9;
        int q = fq & 1, t = fq >> 1;
        int k = (q ? 32 : 0) + ((lane >> 4) << 3) + j;
        int c = t * 16 + (lane & 15);
        float v = (c < HF) ? ldf(sfw, f32, k * HF + c) : ldf(fcw, f32, k * F + (c - HF));
        Wpack[idx] = __float2bfloat16(v);
    } else if (idx < 24576 + 20480) {
        int id2 = idx - 24576;
        int j = id2 & 7, lane = (id2 >> 3) & 63, fq = id2 >> 9;
        int q = fq & 1, t = fq >> 1;
        int k = (q ? 32 : 0) + ((lane >> 4) << 3) + j;
        int c = t * 16 + (lane & 15);
        int r = c >> 4, part = (c >> 3) & 1, h = c & 7;
        float acc = 0.f;
        if (h < H) {
#pragma unroll
            for (int b = 0; b < B; ++b)
                acc += ldf(wc, f32, r * B + b) *
                       ldf(aw, f32, b * (2 * F * H) + (part * F + k) * H + h);
        }
        W2pack[id2] = __float2bfloat16(acc);
    }
    if (f32) {
        for (int i = idx; i < N_NODES * F; i += gridDim.x * blockDim.x)
            featb[i] = __float2bfloat16(((const float*)feat)[i]);
    }
}

// ---------------- K2: GEMM1  P[MPAD,384] = feat @ [self_fc_w | fc_w]  (MFMA)
__global__ __launch_bounds__(256) void k_gemm1(const void* __restrict__ feat,
                                               const __hip_bfloat16* __restrict__ featb,
                                               const __hip_bfloat16* __restrict__ Wpack,
                                               __hip_bfloat16* __restrict__ P,
                                               const int* __restrict__ flags) {
    const int f32 = flags[0];
    const __hip_bfloat16* A = f32 ? featb : (const __hip_bfloat16*)feat;
    const int tid = threadIdx.x;
    const int wave = tid >> 6, lane = tid & 63;
    const int quad = lane >> 4, col = lane & 15;
    const int r0 = blockIdx.x * 16;
    int am = r0 + col;
    if (am >= N_NODES) am = N_NODES - 1;      // clamp: pad rows produce unread garbage

    short8 a0 = *(const short8*)(A + am * F + quad * 8);
    short8 a1 = *(const short8*)(A + am * F + 32 + quad * 8);

    const short8* Wp = (const short8*)Wpack;
    for (int t = wave * 6; t < wave * 6 + 6; ++t) {
        short8 b0 = Wp[(t * 2 + 0) * 64 + lane];
        short8 b1 = Wp[(t * 2 + 1) * 64 + lane];
        float4v acc = {0.f, 0.f, 0.f, 0.f};
        acc = __builtin_amdgcn_mfma_f32_16x16x32_bf16(a0, b0, acc, 0, 0, 0);
        acc = __builtin_amdgcn_mfma_f32_16x16x32_bf16(a1, b1, acc, 0, 0, 0);
        const int cb = t * 16 + col;
#pragma unroll
        for (int j = 0; j < 4; ++j)
            P[(r0 + quad * 4 + j) * NP1 + cb] = __float2bfloat16(acc[j]);
    }
}

// ---------------- K3: GEMM2  a[MPAD,320] = z @ W2  (attention logit halves)
__global__ __launch_bounds__(256) void k_gemm2(const __hip_bfloat16* __restrict__ P,
                                               const __hip_bfloat16* __restrict__ W2pack,
                                               __hip_bfloat16* __restrict__ a) {
    const int tid = threadIdx.x;
    const int wave = tid >> 6, lane = tid & 63;
    const int quad = lane >> 4, col = lane & 15;
    const int r0 = blockIdx.x * 16;
    const int am = r0 + col;                   // rows < MPAD valid in P

    short8 a0 = *(const short8*)(P + am * NP1 + HF + quad * 8);
    short8 a1 = *(const short8*)(P + am * NP1 + HF + 32 + quad * 8);

    const short8* Wp = (const short8*)W2pack;
    for (int t = wave * 5; t < wave * 5 + 5; ++t) {
        short8 b0 = Wp[(t * 2 + 0) * 64 + lane];
        short8 b1 = Wp[(t * 2 + 1) * 64 + lane];
        float4v acc = {0.f, 0.f, 0.f, 0.f};
        acc = __builtin_amdgcn_mfma_f32_16x16x32_bf16(a0, b0, acc, 0, 0, 0);
        acc = __builtin_amdgcn_mfma_f32_16x16x32_bf16(a1, b1, acc, 0, 0, 0);
        const int cb = t * 16 + col;
#pragma unroll
        for (int j = 0; j < 4; ++j)
            a[(r0 + quad * 4 + j) * NA + cb] = __float2bfloat16(acc[j]);
    }
}

// ---------------- K4: degree histogram over dst
__global__ void k_hist(const void* __restrict__ dst, int* __restrict__ deg,
                       const int* __restrict__ flags, int ne) {
    const int i64 = flags[1];
    int e = blockIdx.x * blockDim.x + threadIdx.x;
    if (e >= ne) return;
    atomicAdd(&deg[ldi(dst, i64, e)], 1);
}

// ---------------- K5: single-block exclusive scan -> rowptr, cursor
__global__ __launch_bounds__(1024) void k_scan(const int* __restrict__ deg,
                                               int* __restrict__ rowptr,
                                               int* __restrict__ cursor) {
    __shared__ int tot[1024];
    const int t = threadIdx.x;
    const int base = t * 25;
    int s = 0;
#pragma unroll
    for (int i = 0; i < 25; ++i) {
        int idx = base + i;
        if (idx < N_NODES) s += deg[idx];
    }
    tot[t] = s;
    __syncthreads();
    for (int off = 1; off < 1024; off <<= 1) {
        int v = (t >= off) ? tot[t - off] : 0;
        __syncthreads();
        tot[t] += v;
        __syncthreads();
    }
    int run = (t > 0) ? tot[t - 1] : 0;
#pragma unroll
    for (int i = 0; i < 25; ++i) {
        int idx = base + i;
        if (idx < N_NODES) {
            rowptr[idx] = run;
            cursor[idx] = run;
            run += deg[idx];
        }
    }
    if (t == 1023) rowptr[N_NODES] = tot[1023];
}

// ---------------- K6: scatter edges into CSR order, packed (rel<<16)|src
__global__ void k_scatter(const void* __restrict__ src, const void* __restrict__ dst,
                          const void* __restrict__ et, int* __restrict__ cursor,
                          unsigned* __restrict__ perm, const int* __restrict__ flags,
                          int ne) {
    const int i64 = flags[1];
    int e = blockIdx.x * blockDim.x + threadIdx.x;
    if (e >= ne) return;
    int d = ldi(dst, i64, e);
    int s = ldi(src, i64, e);
    int r = ldi(et, i64, e);
    int pos = atomicAdd(&cursor[d], 1);
    perm[pos] = ((unsigned)r << 16) | (unsigned)s;
}

// ---------------- K7: one wave per dst — att from precomputed logits, aggregate
__global__ __launch_bounds__(256) void k_agg(const __hip_bfloat16* __restrict__ P,
                                             const __hip_bfloat16* __restrict__ a,
                                             const int* __restrict__ rowptr,
                                             const unsigned* __restrict__ perm,
                                             void* __restrict__ out,
                                             const int* __restrict__ flags) {
    const int f32 = flags[0];
    const int tid = threadIdx.x;
    const int lane = tid & 63;
    const int d = blockIdx.x * 4 + (tid >> 6);   // 6250*4 = 25000 exactly
    const int beg = rowptr[d], end = rowptr[d + 1];
    const __hip_bfloat16* ad_base = a + d * NA;

    float acc[H] = {0.f, 0.f, 0.f, 0.f, 0.f};
    for (int e = beg; e < end; ++e) {
        const unsigned pk = perm[e];
        const int s = (int)(pk & 0xFFFFu);
        const int r = (int)(pk >> 16);
        short8 sv = *(const short8*)(a + s * NA + r * 16);       // src logits h0..4 (+pad)
        short8 dv = *(const short8*)(ad_base + r * 16 + 8);      // dst logits h0..4 (+pad)
        const float zs = __bfloat162float(P[s * NP1 + HF + lane]);
#pragma unroll
        for (int h = 0; h < H; ++h) {
            float t = b2f((unsigned short)sv[h]) + b2f((unsigned short)dv[h]);
            float att = fmaxf(t, 0.01f * t);                      // leaky_relu(0.01)
            acc[h] += att * zs;
        }
    }

    const int ob = d * HF + lane;
    if (f32) {
        float* o = (float*)out;
#pragma unroll
        for (int h = 0; h < H; ++h)
            o[ob + h * F] = acc[h] + __bfloat162float(P[d * NP1 + h * F + lane]);
    } else {
        __hip_bfloat16* o = (__hip_bfloat16*)out;
#pragma unroll
        for (int h = 0; h < H; ++h)
            o[ob + h * F] = __float2bfloat16(acc[h] + __bfloat162float(P[d * NP1 + h * F + lane]));
    }
}

extern "C" void kernel_launch(void* const* d_in, const int* in_sizes, int n_in,
                              void* d_out, int out_size, void* d_ws, size_t ws_size,
                              hipStream_t stream) {
    const void* feat = d_in[0];
    const void* src  = d_in[1];
    const void* dst  = d_in[2];
    const void* et   = d_in[3];
    const void* fcw  = d_in[4];
    const void* sfw  = d_in[5];
    const void* aw   = d_in[6];
    const void* wc   = d_in[7];

    // ws layout (~36.9 MB):
    char* w = (char*)d_ws;
    __hip_bfloat16* P      = (__hip_bfloat16*)w;                       w += (size_t)MPAD * NP1 * 2;  // 19,206,144
    __hip_bfloat16* a      = (__hip_bfloat16*)w;                       w += (size_t)MPAD * NA  * 2;  // 16,005,120
    __hip_bfloat16* featb  = a;   // alias: featb (GEMM1 input, f32 mode) dies before GEMM2 writes a
    __hip_bfloat16* Wpack  = (__hip_bfloat16*)w;                       w += 24576 * 2;
    __hip_bfloat16* W2pack = (__hip_bfloat16*)w;                       w += 20480 * 2;
    unsigned* perm = (unsigned*)w;                                     w += (size_t)N_EDGES * 4;
    int* deg       = (int*)w;                                          w += (size_t)N_NODES * 4;
    int* cursor    = (int*)w;                                          w += (size_t)N_NODES * 4;
    int* rowptr    = (int*)w;                                          w += (size_t)(N_NODES + 1) * 4;
    int* flags     = (int*)w;

    k_probe<<<1, 256, 0, stream>>>((const unsigned int*)feat, (const unsigned int*)src, flags);
    k_setup<<<256, 256, 0, stream>>>(feat, fcw, sfw, aw, wc, Wpack, W2pack, featb, deg, flags);
    k_gemm1<<<MPAD / 16, 256, 0, stream>>>(feat, featb, Wpack, P, flags);
    k_gemm2<<<MPAD / 16, 256, 0, stream>>>(P, W2pack, a);
    k_hist<<<(N_EDGES + 255) / 256, 256, 0, stream>>>(dst, deg, flags, N_EDGES);
    k_scan<<<1, 1024, 0, stream>>>(deg, rowptr, cursor);
    k_scatter<<<(N_EDGES + 255) / 256, 256, 0, stream>>>(src, dst, et, cursor, perm, flags, N_EDGES);
    k_agg<<<N_NODES / 4, 256, 0, stream>>>(P, a, rowptr, perm, d_out, flags);
}

// Round 7
// 234.089 us; speedup vs baseline: 2.5413x; 1.0351x over previous
//
#include <hip/hip_runtime.h>
#include <hip/hip_bf16.h>

#define N_NODES 25000
#define N_EDGES 320000
#define F 64
#define H 5
#define R 20
#define B 10
#define HF 320            // H*F
#define MPAD 25008        // 1563*16 rows

typedef __attribute__((ext_vector_type(8))) short short8;
typedef __attribute__((ext_vector_type(4))) float float4v;

__device__ __forceinline__ float ldf(const void* p, int f32, int i) {
    if (f32) return ((const float*)p)[i];
    else     return __bfloat162float(((const __hip_bfloat16*)p)[i]);
}
__device__ __forceinline__ int ldi(const void* p, int i64, int i) {
    if (i64) return ((const int*)p)[2 * i];
    else     return ((const int*)p)[i];
}
__device__ __forceinline__ float b2f(unsigned short u) {
    union { unsigned u32; float f; } v; v.u32 = ((unsigned)u) << 16; return v.f;
}

// ---------------- K0: blocks 0..97 zero deg; block 98 probes dtypes
__global__ void k0_init(const unsigned int* __restrict__ feat_raw,
                        const unsigned int* __restrict__ src_raw,
                        int* __restrict__ flags, int* __restrict__ deg) {
    const int b = blockIdx.x, tid = threadIdx.x;
    if (b < 98) {
        int i = b * 256 + tid;
        if (i < N_NODES) deg[i] = 0;
        return;
    }
    __shared__ int sSane, sZero;
    if (tid == 0) { sSane = 0; sZero = 0; }
    __syncthreads();
    int sane = 0, zero = 0;
    for (int i = tid; i < 4096; i += 256) {
        unsigned w = feat_raw[i];
        unsigned e = (w >> 7) & 0xFF;
        if (e >= 110 && e <= 140) sane++;
        if (src_raw[2 * i + 1] == 0) zero++;
    }
    atomicAdd(&sSane, sane);
    atomicAdd(&sZero, zero);
    __syncthreads();
    if (tid == 0) {
        flags[0] = (sSane < 2048) ? 1 : 0;
        flags[1] = (sZero > 2048) ? 1 : 0;
    }
}

// ---------------- K1: blocks 0..175 pack weights; blocks 176.. hist + featb cvt
__global__ void k1_setup(const void* __restrict__ feat, const void* __restrict__ fcw,
                         const void* __restrict__ sfw, const void* __restrict__ aw,
                         const void* __restrict__ wc, const void* __restrict__ dst,
                         __hip_bfloat16* __restrict__ Wpack,
                         __hip_bfloat16* __restrict__ W2pack,
                         __hip_bfloat16* __restrict__ featb,
                         int* __restrict__ deg, const int* __restrict__ flags) {
    const int f32 = flags[0], i64 = flags[1];
    const int b = blockIdx.x, tid = threadIdx.x;
    if (b < 176) {
        const int idx = b * 256 + tid;
        if (idx < 24576) {
            int j = idx & 7, lane = (idx >> 3) & 63, fq = idx >> 9;
            int q = fq & 1, t = fq >> 1;
            int k = (q ? 32 : 0) + ((lane >> 4) << 3) + j;
            int c = t * 16 + (lane & 15);
            float v = (c < HF) ? ldf(sfw, f32, k * HF + c) : ldf(fcw, f32, k * F + (c - HF));
            Wpack[idx] = __float2bfloat16(v);
        } else if (idx < 24576 + 20480) {
            int id2 = idx - 24576;
            int j = id2 & 7, lane = (id2 >> 3) & 63, fq = id2 >> 9;
            int q = fq & 1, t = fq >> 1;
            int k = (q ? 32 : 0) + ((lane >> 4) << 3) + j;
            int c = t * 16 + (lane & 15);
            int r = c >> 4, part = (c >> 3) & 1, h = c & 7;
            float acc = 0.f;
            if (h < H) {
#pragma unroll
                for (int bb = 0; bb < B; ++bb)
                    acc += ldf(wc, f32, r * B + bb) *
                           ldf(aw, f32, bb * (2 * F * H) + (part * F + k) * H + h);
            }
            W2pack[id2] = __float2bfloat16(acc);
        }
    } else {
        const int e = (b - 176) * 256 + tid;
        if (e < N_EDGES) atomicAdd(&deg[ldi(dst, i64, e)], 1);
        if (f32) {
            for (int i = e; i < N_NODES * F; i += 1250 * 256)
                featb[i] = __float2bfloat16(((const float*)feat)[i]);
        }
    }
}

// ---------------- K2: blocks 0..1562 GEMM1 (selfz+zc); block 1563 CSR scan
__global__ __launch_bounds__(256) void k2_gemm1(const void* __restrict__ feat,
                                                const __hip_bfloat16* __restrict__ featb,
                                                const __hip_bfloat16* __restrict__ Wpack,
                                                __hip_bfloat16* __restrict__ selfz,
                                                __hip_bfloat16* __restrict__ zc,
                                                const int* __restrict__ deg,
                                                int* __restrict__ rowptr,
                                                int* __restrict__ cursor,
                                                const int* __restrict__ flags) {
    if (blockIdx.x == 1563) {               // ---- scan block (hidden under GEMM)
        __shared__ int tot[256];
        const int t = threadIdx.x;
        const int base = t * 98;            // 256*98 = 25088 >= 25000
        int s = 0;
#pragma unroll
        for (int i = 0; i < 98; ++i) {
            int idx = base + i;
            if (idx < N_NODES) s += deg[idx];
        }
        tot[t] = s;
        __syncthreads();
        for (int off = 1; off < 256; off <<= 1) {
            int v = (t >= off) ? tot[t - off] : 0;
            __syncthreads();
            tot[t] += v;
            __syncthreads();
        }
        int run = (t > 0) ? tot[t - 1] : 0;
#pragma unroll
        for (int i = 0; i < 98; ++i) {
            int idx = base + i;
            if (idx < N_NODES) { rowptr[idx] = run; cursor[idx] = run; run += deg[idx]; }
        }
        if (t == 255) rowptr[N_NODES] = tot[255];
        return;
    }
    const int f32 = flags[0];
    const __hip_bfloat16* A = f32 ? featb : (const __hip_bfloat16*)feat;
    const int tid = threadIdx.x;
    const int wave = tid >> 6, lane = tid & 63;
    const int quad = lane >> 4, col = lane & 15;
    const int r0 = blockIdx.x * 16;
    int am = r0 + col;
    if (am >= N_NODES) am = N_NODES - 1;

    short8 a0 = *(const short8*)(A + am * F + quad * 8);
    short8 a1 = *(const short8*)(A + am * F + 32 + quad * 8);

    const short8* Wp = (const short8*)Wpack;
    for (int tt = 0; tt < 6; ++tt) {
        const int t = wave * 6 + tt;
        short8 b0 = Wp[(t * 2 + 0) * 64 + lane];
        short8 b1 = Wp[(t * 2 + 1) * 64 + lane];
        float4v acc = {0.f, 0.f, 0.f, 0.f};
        acc = __builtin_amdgcn_mfma_f32_16x16x32_bf16(a0, b0, acc, 0, 0, 0);
        acc = __builtin_amdgcn_mfma_f32_16x16x32_bf16(a1, b1, acc, 0, 0, 0);
        const int cb = t * 16 + col;
        if (t < 20) {
#pragma unroll
            for (int j = 0; j < 4; ++j)
                selfz[(r0 + quad * 4 + j) * HF + cb] = __float2bfloat16(acc[j]);
        } else {
#pragma unroll
            for (int j = 0; j < 4; ++j)
                zc[(r0 + quad * 4 + j) * F + (cb - HF)] = __float2bfloat16(acc[j]);
        }
    }
}

// ---------------- K3: blocks 0..1562 GEMM2 (a_src/a_dst); blocks 1563.. scatter
__global__ __launch_bounds__(256) void k3_gemm2(const __hip_bfloat16* __restrict__ zc,
                                                const __hip_bfloat16* __restrict__ W2pack,
                                                __hip_bfloat16* __restrict__ a_src,
                                                __hip_bfloat16* __restrict__ a_dst,
                                                const void* __restrict__ src,
                                                const void* __restrict__ dst,
                                                const void* __restrict__ et,
                                                int* __restrict__ cursor,
                                                unsigned* __restrict__ perm,
                                                const int* __restrict__ flags) {
    const int tid = threadIdx.x;
    if (blockIdx.x >= 1563) {               // ---- scatter blocks
        const int i64 = flags[1];
        const int e = (blockIdx.x - 1563) * 256 + tid;
        if (e >= N_EDGES) return;
        int d = ldi(dst, i64, e);
        int s = ldi(src, i64, e);
        int r = ldi(et, i64, e);
        int pos = atomicAdd(&cursor[d], 1);
        perm[pos] = ((unsigned)r << 16) | (unsigned)s;
        return;
    }
    const int wave = tid >> 6, lane = tid & 63;
    const int quad = lane >> 4, col = lane & 15;
    const int r0 = blockIdx.x * 16;
    const int am = r0 + col;

    short8 a0 = *(const short8*)(zc + am * F + quad * 8);
    short8 a1 = *(const short8*)(zc + am * F + 32 + quad * 8);

    const short8* Wp = (const short8*)W2pack;
    for (int tt = 0; tt < 5; ++tt) {
        const int t = wave * 5 + tt;
        short8 b0 = Wp[(t * 2 + 0) * 64 + lane];
        short8 b1 = Wp[(t * 2 + 1) * 64 + lane];
        float4v acc = {0.f, 0.f, 0.f, 0.f};
        acc = __builtin_amdgcn_mfma_f32_16x16x32_bf16(a0, b0, acc, 0, 0, 0);
        acc = __builtin_amdgcn_mfma_f32_16x16x32_bf16(a1, b1, acc, 0, 0, 0);
        const int cb = t * 16 + col;
        const int r = cb >> 4, part = (cb >> 3) & 1, h = cb & 7;
        __hip_bfloat16* dsta = part ? a_dst : a_src;
#pragma unroll
        for (int j = 0; j < 4; ++j)
            dsta[(r0 + quad * 4 + j) * 160 + r * 8 + h] = __float2bfloat16(acc[j]);
    }
}

// ---------------- K4: one wave per dst — logits add + leaky + weighted sum
__global__ __launch_bounds__(256) void k4_agg(const __hip_bfloat16* __restrict__ selfz,
                                              const unsigned short* __restrict__ zc,
                                              const __hip_bfloat16* __restrict__ a_src,
                                              const __hip_bfloat16* __restrict__ a_dst,
                                              const int* __restrict__ rowptr,
                                              const unsigned* __restrict__ perm,
                                              void* __restrict__ out,
                                              const int* __restrict__ flags) {
    __shared__ short sdv[4][160];
    const int f32 = flags[0];
    const int tid = threadIdx.x;
    const int wid = tid >> 6, lane = tid & 63;
    const int d = blockIdx.x * 4 + wid;       // 6250*4 = 25000

    if (lane < 20)
        *(short8*)&sdv[wid][lane * 8] = *(const short8*)((const short*)a_dst + d * 160 + lane * 8);
    __syncthreads();

    const int beg = rowptr[d], end = rowptr[d + 1];
    const short* as = (const short*)a_src;

    float acc[H] = {0.f, 0.f, 0.f, 0.f, 0.f};
    int e = beg;
    for (; e + 1 < end; e += 2) {
        const unsigned pk0 = perm[e], pk1 = perm[e + 1];
        const int s0 = (int)(pk0 & 0xFFFFu), r0 = (int)(pk0 >> 16);
        const int s1 = (int)(pk1 & 0xFFFFu), r1 = (int)(pk1 >> 16);
        short8 sv0 = *(const short8*)(as + s0 * 160 + r0 * 8);
        short8 sv1 = *(const short8*)(as + s1 * 160 + r1 * 8);
        const float zs0 = b2f(zc[s0 * F + lane]);
        const float zs1 = b2f(zc[s1 * F + lane]);
        short8 dv0 = *(const short8*)&sdv[wid][r0 * 8];
        short8 dv1 = *(const short8*)&sdv[wid][r1 * 8];
#pragma unroll
        for (int h = 0; h < H; ++h) {
            float t0 = b2f((unsigned short)sv0[h]) + b2f((unsigned short)dv0[h]);
            float t1 = b2f((unsigned short)sv1[h]) + b2f((unsigned short)dv1[h]);
            acc[h] += fmaxf(t0, 0.01f * t0) * zs0;
            acc[h] += fmaxf(t1, 0.01f * t1) * zs1;
        }
    }
    for (; e < end; ++e) {
        const unsigned pk = perm[e];
        const int s = (int)(pk & 0xFFFFu), r = (int)(pk >> 16);
        short8 sv = *(const short8*)(as + s * 160 + r * 8);
        const float zs = b2f(zc[s * F + lane]);
        short8 dv = *(const short8*)&sdv[wid][r * 8];
#pragma unroll
        for (int h = 0; h < H; ++h) {
            float t = b2f((unsigned short)sv[h]) + b2f((unsigned short)dv[h]);
            acc[h] += fmaxf(t, 0.01f * t) * zs;
        }
    }

    const int ob = d * HF + lane;
    if (f32) {
        float* o = (float*)out;
#pragma unroll
        for (int h = 0; h < H; ++h)
            o[ob + h * F] = acc[h] + __bfloat162float(selfz[ob + h * F]);
    } else {
        __hip_bfloat16* o = (__hip_bfloat16*)out;
#pragma unroll
        for (int h = 0; h < H; ++h)
            o[ob + h * F] = __float2bfloat16(acc[h] + __bfloat162float(selfz[ob + h * F]));
    }
}

extern "C" void kernel_launch(void* const* d_in, const int* in_sizes, int n_in,
                              void* d_out, int out_size, void* d_ws, size_t ws_size,
                              hipStream_t stream) {
    const void* feat = d_in[0];
    const void* src  = d_in[1];
    const void* dst  = d_in[2];
    const void* et   = d_in[3];
    const void* fcw  = d_in[4];
    const void* sfw  = d_in[5];
    const void* aw   = d_in[6];
    const void* wc   = d_in[7];

    // ws (~36.9 MB): selfz | zc | a_src | a_dst(alias featb) | Wpack | W2pack | perm | deg | cursor | rowptr | flags
    char* w = (char*)d_ws;
    __hip_bfloat16* selfz  = (__hip_bfloat16*)w;  w += (size_t)MPAD * HF * 2;    // 16.0 MB
    __hip_bfloat16* zc     = (__hip_bfloat16*)w;  w += (size_t)MPAD * F * 2;     // 3.2 MB
    __hip_bfloat16* a_src  = (__hip_bfloat16*)w;  w += (size_t)MPAD * 160 * 2;   // 8.0 MB
    __hip_bfloat16* a_dst  = (__hip_bfloat16*)w;  w += (size_t)MPAD * 160 * 2;   // 8.0 MB
    __hip_bfloat16* featb  = a_dst;  // featb dies (last read K2) before a_dst written (K3)
    __hip_bfloat16* Wpack  = (__hip_bfloat16*)w;  w += 24576 * 2;
    __hip_bfloat16* W2pack = (__hip_bfloat16*)w;  w += 20480 * 2;
    unsigned* perm = (unsigned*)w;                w += (size_t)N_EDGES * 4;
    int* deg       = (int*)w;                     w += (size_t)N_NODES * 4;
    int* cursor    = (int*)w;                     w += (size_t)N_NODES * 4;
    int* rowptr    = (int*)w;                     w += (size_t)(N_NODES + 1) * 4;
    int* flags     = (int*)w;

    k0_init<<<99, 256, 0, stream>>>((const unsigned int*)feat, (const unsigned int*)src, flags, deg);
    k1_setup<<<176 + 1250, 256, 0, stream>>>(feat, fcw, sfw, aw, wc, dst, Wpack, W2pack, featb, deg, flags);
    k2_gemm1<<<1564, 256, 0, stream>>>(feat, featb, Wpack, selfz, zc, deg, rowptr, cursor, flags);
    k3_gemm2<<<1563 + 1250, 256, 0, stream>>>(zc, W2pack, a_src, a_dst, src, dst, et, cursor, perm, flags);
    k4_agg<<<N_NODES / 4, 256, 0, stream>>>(selfz, (const unsigned short*)zc, a_src, a_dst, rowptr, perm, d_out, flags);
}

// Round 8
// 222.596 us; speedup vs baseline: 2.6725x; 1.0516x over previous
//
#include <hip/hip_runtime.h>
#include <hip/hip_bf16.h>

#define N_NODES 25000
#define N_EDGES 320000
#define F 64
#define H 5
#define R 20
#define B 10
#define HF 320            // H*F
#define MPAD 25008        // 1563*16 rows

typedef __attribute__((ext_vector_type(8))) short short8;
typedef __attribute__((ext_vector_type(4))) float float4v;

__device__ __forceinline__ float ldf(const void* p, int f32, int i) {
    if (f32) return ((const float*)p)[i];
    else     return __bfloat162float(((const __hip_bfloat16*)p)[i]);
}
__device__ __forceinline__ int ldi(const void* p, int i64, int i) {
    if (i64) return ((const int*)p)[2 * i];
    else     return ((const int*)p)[i];
}
__device__ __forceinline__ float b2f(unsigned short u) {
    union { unsigned u32; float f; } v; v.u32 = ((unsigned)u) << 16; return v.f;
}

// ---------------- K0: blocks 0..97 zero deg; block 98 probes dtypes
__global__ void k0_init(const unsigned int* __restrict__ feat_raw,
                        const unsigned int* __restrict__ src_raw,
                        int* __restrict__ flags, int* __restrict__ deg) {
    const int b = blockIdx.x, tid = threadIdx.x;
    if (b < 98) {
        int i = b * 256 + tid;
        if (i < N_NODES) deg[i] = 0;
        return;
    }
    __shared__ int sSane, sZero;
    if (tid == 0) { sSane = 0; sZero = 0; }
    __syncthreads();
    int sane = 0, zero = 0;
    for (int i = tid; i < 4096; i += 256) {
        unsigned w = feat_raw[i];
        unsigned e = (w >> 7) & 0xFF;
        if (e >= 110 && e <= 140) sane++;
        if (src_raw[2 * i + 1] == 0) zero++;
    }
    atomicAdd(&sSane, sane);
    atomicAdd(&sZero, zero);
    __syncthreads();
    if (tid == 0) {
        flags[0] = (sSane < 2048) ? 1 : 0;
        flags[1] = (sZero > 2048) ? 1 : 0;
    }
}

// ---------------- K1: blocks 0..175 pack weights; blocks 176.. hist + featb cvt
__global__ void k1_setup(const void* __restrict__ feat, const void* __restrict__ fcw,
                         const void* __restrict__ sfw, const void* __restrict__ aw,
                         const void* __restrict__ wc, const void* __restrict__ dst,
                         __hip_bfloat16* __restrict__ Wpack,
                         __hip_bfloat16* __restrict__ W2pack,
                         __hip_bfloat16* __restrict__ featb,
                         int* __restrict__ deg, const int* __restrict__ flags) {
    const int f32 = flags[0], i64 = flags[1];
    const int b = blockIdx.x, tid = threadIdx.x;
    if (b < 176) {
        const int idx = b * 256 + tid;
        if (idx < 24576) {
            int j = idx & 7, lane = (idx >> 3) & 63, fq = idx >> 9;
            int q = fq & 1, t = fq >> 1;
            int k = (q ? 32 : 0) + ((lane >> 4) << 3) + j;
            int c = t * 16 + (lane & 15);
            float v = (c < HF) ? ldf(sfw, f32, k * HF + c) : ldf(fcw, f32, k * F + (c - HF));
            Wpack[idx] = __float2bfloat16(v);
        } else if (idx < 24576 + 20480) {
            int id2 = idx - 24576;
            int j = id2 & 7, lane = (id2 >> 3) & 63, fq = id2 >> 9;
            int q = fq & 1, t = fq >> 1;
            int k = (q ? 32 : 0) + ((lane >> 4) << 3) + j;
            int c = t * 16 + (lane & 15);
            int r = c >> 4, part = (c >> 3) & 1, h = c & 7;
            float acc = 0.f;
            if (h < H) {
#pragma unroll
                for (int bb = 0; bb < B; ++bb)
                    acc += ldf(wc, f32, r * B + bb) *
                           ldf(aw, f32, bb * (2 * F * H) + (part * F + k) * H + h);
            }
            W2pack[id2] = __float2bfloat16(acc);
        }
    } else {
        const int e = (b - 176) * 256 + tid;
        if (e < N_EDGES) atomicAdd(&deg[ldi(dst, i64, e)], 1);
        if (f32) {
            for (int i = e; i < N_NODES * F; i += 1250 * 256)
                featb[i] = __float2bfloat16(((const float*)feat)[i]);
        }
    }
}

// ---------------- K2: GEMM1 (selfz+zc), branch-free per-wave tile split
__global__ __launch_bounds__(256) void k2_gemm1(const void* __restrict__ feat,
                                                const __hip_bfloat16* __restrict__ featb,
                                                const __hip_bfloat16* __restrict__ Wpack,
                                                __hip_bfloat16* __restrict__ selfz,
                                                __hip_bfloat16* __restrict__ zc,
                                                const int* __restrict__ flags) {
    const int f32 = flags[0];
    const __hip_bfloat16* A = f32 ? featb : (const __hip_bfloat16*)feat;
    const int tid = threadIdx.x;
    const int wave = tid >> 6, lane = tid & 63;
    const int quad = lane >> 4, col = lane & 15;
    const int r0 = blockIdx.x * 16;
    int am = r0 + col;
    if (am >= N_NODES) am = N_NODES - 1;

    short8 a0 = *(const short8*)(A + am * F + quad * 8);
    short8 a1 = *(const short8*)(A + am * F + 32 + quad * 8);

    const short8* Wp = (const short8*)Wpack;
    // selfz tiles: t = wave*5 .. wave*5+4  (covers 0..19)
#pragma unroll
    for (int tt = 0; tt < 5; ++tt) {
        const int t = wave * 5 + tt;
        short8 b0 = Wp[(t * 2 + 0) * 64 + lane];
        short8 b1 = Wp[(t * 2 + 1) * 64 + lane];
        float4v acc = {0.f, 0.f, 0.f, 0.f};
        acc = __builtin_amdgcn_mfma_f32_16x16x32_bf16(a0, b0, acc, 0, 0, 0);
        acc = __builtin_amdgcn_mfma_f32_16x16x32_bf16(a1, b1, acc, 0, 0, 0);
        const int cb = t * 16 + col;
#pragma unroll
        for (int j = 0; j < 4; ++j)
            selfz[(r0 + quad * 4 + j) * HF + cb] = __float2bfloat16(acc[j]);
    }
    // zc tile: t = 20 + wave  (covers 20..23)
    {
        const int t = 20 + wave;
        short8 b0 = Wp[(t * 2 + 0) * 64 + lane];
        short8 b1 = Wp[(t * 2 + 1) * 64 + lane];
        float4v acc = {0.f, 0.f, 0.f, 0.f};
        acc = __builtin_amdgcn_mfma_f32_16x16x32_bf16(a0, b0, acc, 0, 0, 0);
        acc = __builtin_amdgcn_mfma_f32_16x16x32_bf16(a1, b1, acc, 0, 0, 0);
        const int cb = wave * 16 + col;
#pragma unroll
        for (int j = 0; j < 4; ++j)
            zc[(r0 + quad * 4 + j) * F + cb] = __float2bfloat16(acc[j]);
    }
}

// ---------------- K2b: single-block exclusive scan -> rowptr, cursor
__global__ __launch_bounds__(1024) void k_scan(const int* __restrict__ deg,
                                               int* __restrict__ rowptr,
                                               int* __restrict__ cursor) {
    __shared__ int tot[1024];
    const int t = threadIdx.x;
    const int base = t * 25;                   // 1024*25 = 25600 >= 25000
    int s = 0;
#pragma unroll
    for (int i = 0; i < 25; ++i) {
        int idx = base + i;
        if (idx < N_NODES) s += deg[idx];
    }
    tot[t] = s;
    __syncthreads();
    for (int off = 1; off < 1024; off <<= 1) {
        int v = (t >= off) ? tot[t - off] : 0;
        __syncthreads();
        tot[t] += v;
        __syncthreads();
    }
    int run = (t > 0) ? tot[t - 1] : 0;
#pragma unroll
    for (int i = 0; i < 25; ++i) {
        int idx = base + i;
        if (idx < N_NODES) { rowptr[idx] = run; cursor[idx] = run; run += deg[idx]; }
    }
    if (t == 1023) rowptr[N_NODES] = tot[1023];
}

// ---------------- K3: blocks 0..1562 GEMM2 (a_src/a_dst); blocks 1563.. scatter
__global__ __launch_bounds__(256) void k3_gemm2(const __hip_bfloat16* __restrict__ zc,
                                                const __hip_bfloat16* __restrict__ W2pack,
                                                __hip_bfloat16* __restrict__ a_src,
                                                __hip_bfloat16* __restrict__ a_dst,
                                                const void* __restrict__ src,
                                                const void* __restrict__ dst,
                                                const void* __restrict__ et,
                                                int* __restrict__ cursor,
                                                unsigned* __restrict__ perm,
                                                const int* __restrict__ flags) {
    const int tid = threadIdx.x;
    if (blockIdx.x >= 1563) {               // ---- scatter blocks
        const int i64 = flags[1];
        const int e = (blockIdx.x - 1563) * 256 + tid;
        if (e >= N_EDGES) return;
        int d = ldi(dst, i64, e);
        int s = ldi(src, i64, e);
        int r = ldi(et, i64, e);
        int pos = atomicAdd(&cursor[d], 1);
        perm[pos] = ((unsigned)r << 16) | (unsigned)s;
        return;
    }
    const int wave = tid >> 6, lane = tid & 63;
    const int quad = lane >> 4, col = lane & 15;
    const int r0 = blockIdx.x * 16;
    const int am = r0 + col;

    short8 a0 = *(const short8*)(zc + am * F + quad * 8);
    short8 a1 = *(const short8*)(zc + am * F + 32 + quad * 8);

    const short8* Wp = (const short8*)W2pack;
#pragma unroll
    for (int tt = 0; tt < 5; ++tt) {
        const int t = wave * 5 + tt;
        short8 b0 = Wp[(t * 2 + 0) * 64 + lane];
        short8 b1 = Wp[(t * 2 + 1) * 64 + lane];
        float4v acc = {0.f, 0.f, 0.f, 0.f};
        acc = __builtin_amdgcn_mfma_f32_16x16x32_bf16(a0, b0, acc, 0, 0, 0);
        acc = __builtin_amdgcn_mfma_f32_16x16x32_bf16(a1, b1, acc, 0, 0, 0);
        const int cb = t * 16 + col;
        const int r = cb >> 4, part = (cb >> 3) & 1, h = cb & 7;
        __hip_bfloat16* dsta = part ? a_dst : a_src;
#pragma unroll
        for (int j = 0; j < 4; ++j)
            dsta[(r0 + quad * 4 + j) * 160 + r * 8 + h] = __float2bfloat16(acc[j]);
    }
}

// ---------------- K4: one wave per dst — logits add + leaky + weighted sum
__global__ __launch_bounds__(256) void k4_agg(const __hip_bfloat16* __restrict__ selfz,
                                              const unsigned short* __restrict__ zc,
                                              const __hip_bfloat16* __restrict__ a_src,
                                              const __hip_bfloat16* __restrict__ a_dst,
                                              const int* __restrict__ rowptr,
                                              const unsigned* __restrict__ perm,
                                              void* __restrict__ out,
                                              const int* __restrict__ flags) {
    __shared__ short sdv[4][160];
    const int f32 = flags[0];
    const int tid = threadIdx.x;
    const int wid = tid >> 6, lane = tid & 63;
    const int d = blockIdx.x * 4 + wid;       // 6250*4 = 25000

    if (lane < 20)
        *(short8*)&sdv[wid][lane * 8] = *(const short8*)((const short*)a_dst + d * 160 + lane * 8);
    __syncthreads();

    const int beg = rowptr[d], end = rowptr[d + 1];
    const short* as = (const short*)a_src;

    float acc[H] = {0.f, 0.f, 0.f, 0.f, 0.f};
    int e = beg;
    for (; e + 1 < end; e += 2) {
        const unsigned pk0 = perm[e], pk1 = perm[e + 1];
        const int s0 = (int)(pk0 & 0xFFFFu), r0 = (int)(pk0 >> 16);
        const int s1 = (int)(pk1 & 0xFFFFu), r1 = (int)(pk1 >> 16);
        short8 sv0 = *(const short8*)(as + s0 * 160 + r0 * 8);
        short8 sv1 = *(const short8*)(as + s1 * 160 + r1 * 8);
        const float zs0 = b2f(zc[s0 * F + lane]);
        const float zs1 = b2f(zc[s1 * F + lane]);
        short8 dv0 = *(const short8*)&sdv[wid][r0 * 8];
        short8 dv1 = *(const short8*)&sdv[wid][r1 * 8];
#pragma unroll
        for (int h = 0; h < H; ++h) {
            float t0 = b2f((unsigned short)sv0[h]) + b2f((unsigned short)dv0[h]);
            float t1 = b2f((unsigned short)sv1[h]) + b2f((unsigned short)dv1[h]);
            acc[h] += fmaxf(t0, 0.01f * t0) * zs0;
            acc[h] += fmaxf(t1, 0.01f * t1) * zs1;
        }
    }
    for (; e < end; ++e) {
        const unsigned pk = perm[e];
        const int s = (int)(pk & 0xFFFFu), r = (int)(pk >> 16);
        short8 sv = *(const short8*)(as + s * 160 + r * 8);
        const float zs = b2f(zc[s * F + lane]);
        short8 dv = *(const short8*)&sdv[wid][r * 8];
#pragma unroll
        for (int h = 0; h < H; ++h) {
            float t = b2f((unsigned short)sv[h]) + b2f((unsigned short)dv[h]);
            acc[h] += fmaxf(t, 0.01f * t) * zs;
        }
    }

    const int ob = d * HF + lane;
    if (f32) {
        float* o = (float*)out;
#pragma unroll
        for (int h = 0; h < H; ++h)
            o[ob + h * F] = acc[h] + __bfloat162float(selfz[ob + h * F]);
    } else {
        __hip_bfloat16* o = (__hip_bfloat16*)out;
#pragma unroll
        for (int h = 0; h < H; ++h)
            o[ob + h * F] = __float2bfloat16(acc[h] + __bfloat162float(selfz[ob + h * F]));
    }
}

extern "C" void kernel_launch(void* const* d_in, const int* in_sizes, int n_in,
                              void* d_out, int out_size, void* d_ws, size_t ws_size,
                              hipStream_t stream) {
    const void* feat = d_in[0];
    const void* src  = d_in[1];
    const void* dst  = d_in[2];
    const void* et   = d_in[3];
    const void* fcw  = d_in[4];
    const void* sfw  = d_in[5];
    const void* aw   = d_in[6];
    const void* wc   = d_in[7];

    // ws (~36.9 MB): selfz | zc | a_src | a_dst(alias featb) | Wpack | W2pack | perm | deg | cursor | rowptr | flags
    char* w = (char*)d_ws;
    __hip_bfloat16* selfz  = (__hip_bfloat16*)w;  w += (size_t)MPAD * HF * 2;    // 16.0 MB
    __hip_bfloat16* zc     = (__hip_bfloat16*)w;  w += (size_t)MPAD * F * 2;     // 3.2 MB
    __hip_bfloat16* a_src  = (__hip_bfloat16*)w;  w += (size_t)MPAD * 160 * 2;   // 8.0 MB
    __hip_bfloat16* a_dst  = (__hip_bfloat16*)w;  w += (size_t)MPAD * 160 * 2;   // 8.0 MB
    __hip_bfloat16* featb  = a_dst;  // featb dies (last read K2) before a_dst written (K3)
    __hip_bfloat16* Wpack  = (__hip_bfloat16*)w;  w += 24576 * 2;
    __hip_bfloat16* W2pack = (__hip_bfloat16*)w;  w += 20480 * 2;
    unsigned* perm = (unsigned*)w;                w += (size_t)N_EDGES * 4;
    int* deg       = (int*)w;                     w += (size_t)N_NODES * 4;
    int* cursor    = (int*)w;                     w += (size_t)N_NODES * 4;
    int* rowptr    = (int*)w;                     w += (size_t)(N_NODES + 1) * 4;
    int* flags     = (int*)w;

    k0_init<<<99, 256, 0, stream>>>((const unsigned int*)feat, (const unsigned int*)src, flags, deg);
    k1_setup<<<176 + 1250, 256, 0, stream>>>(feat, fcw, sfw, aw, wc, dst, Wpack, W2pack, featb, deg, flags);
    k2_gemm1<<<1563, 256, 0, stream>>>(feat, featb, Wpack, selfz, zc, flags);
    k_scan<<<1, 1024, 0, stream>>>(deg, rowptr, cursor);
    k3_gemm2<<<1563 + 1250, 256, 0, stream>>>(zc, W2pack, a_src, a_dst, src, dst, et, cursor, perm, flags);
    k4_agg<<<N_NODES / 4, 256, 0, stream>>>(selfz, (const unsigned short*)zc, a_src, a_dst, rowptr, perm, d_out, flags);
}

// Round 9
// 190.471 us; speedup vs baseline: 3.1232x; 1.1687x over previous
//
#include <hip/hip_runtime.h>
#include <hip/hip_bf16.h>

#define N_NODES 25000
#define N_EDGES 320000
#define F 64
#define H 5
#define R 20
#define B 10
#define HF 320            // H*F
#define MPAD 25008        // 1563*16 rows

typedef __attribute__((ext_vector_type(8))) short short8;
typedef __attribute__((ext_vector_type(4))) float float4v;

__device__ __forceinline__ float ldf(const void* p, int f32, int i) {
    if (f32) return ((const float*)p)[i];
    else     return __bfloat162float(((const __hip_bfloat16*)p)[i]);
}
__device__ __forceinline__ int ldi(const void* p, int i64, int i) {
    if (i64) return ((const int*)p)[2 * i];
    else     return ((const int*)p)[i];
}
__device__ __forceinline__ float b2f(unsigned short u) {
    union { unsigned u32; float f; } v; v.u32 = ((unsigned)u) << 16; return v.f;
}

// ---------------- K0: blocks 0..97 zero deg; block 98 probes dtypes
__global__ void k0_init(const unsigned int* __restrict__ feat_raw,
                        const unsigned int* __restrict__ src_raw,
                        int* __restrict__ flags, int* __restrict__ deg) {
    const int b = blockIdx.x, tid = threadIdx.x;
    if (b < 98) {
        int i = b * 256 + tid;
        if (i < N_NODES) deg[i] = 0;
        return;
    }
    __shared__ int sSane, sZero;
    if (tid == 0) { sSane = 0; sZero = 0; }
    __syncthreads();
    int sane = 0, zero = 0;
    for (int i = tid; i < 4096; i += 256) {
        unsigned w = feat_raw[i];
        unsigned e = (w >> 7) & 0xFF;
        if (e >= 110 && e <= 140) sane++;
        if (src_raw[2 * i + 1] == 0) zero++;
    }
    atomicAdd(&sSane, sane);
    atomicAdd(&sZero, zero);
    __syncthreads();
    if (tid == 0) {
        flags[0] = (sSane < 2048) ? 1 : 0;
        flags[1] = (sZero > 2048) ? 1 : 0;
    }
}

// ---------------- K1: blocks 0..175 pack weights; blocks 176.. hist + featb cvt
__global__ void k1_setup(const void* __restrict__ feat, const void* __restrict__ fcw,
                         const void* __restrict__ sfw, const void* __restrict__ aw,
                         const void* __restrict__ wc, const void* __restrict__ dst,
                         __hip_bfloat16* __restrict__ Wpack,
                         __hip_bfloat16* __restrict__ W2pack,
                         __hip_bfloat16* __restrict__ featb,
                         int* __restrict__ deg, const int* __restrict__ flags) {
    const int f32 = flags[0], i64 = flags[1];
    const int b = blockIdx.x, tid = threadIdx.x;
    if (b < 176) {
        const int idx = b * 256 + tid;
        if (idx < 24576) {
            int j = idx & 7, lane = (idx >> 3) & 63, fq = idx >> 9;
            int q = fq & 1, t = fq >> 1;
            int k = (q ? 32 : 0) + ((lane >> 4) << 3) + j;
            int c = t * 16 + (lane & 15);
            float v = (c < HF) ? ldf(sfw, f32, k * HF + c) : ldf(fcw, f32, k * F + (c - HF));
            Wpack[idx] = __float2bfloat16(v);
        } else if (idx < 24576 + 20480) {
            int id2 = idx - 24576;
            int j = id2 & 7, lane = (id2 >> 3) & 63, fq = id2 >> 9;
            int q = fq & 1, t = fq >> 1;
            int k = (q ? 32 : 0) + ((lane >> 4) << 3) + j;
            int c = t * 16 + (lane & 15);
            int r = c >> 4, part = (c >> 3) & 1, h = c & 7;
            float acc = 0.f;
            if (h < H) {
#pragma unroll
                for (int bb = 0; bb < B; ++bb)
                    acc += ldf(wc, f32, r * B + bb) *
                           ldf(aw, f32, bb * (2 * F * H) + (part * F + k) * H + h);
            }
            W2pack[id2] = __float2bfloat16(acc);
        }
    } else {
        const int e = (b - 176) * 256 + tid;
        if (e < N_EDGES) atomicAdd(&deg[ldi(dst, i64, e)], 1);
        if (f32) {
            for (int i = e; i < N_NODES * F; i += 1250 * 256)
                featb[i] = __float2bfloat16(((const float*)feat)[i]);
        }
    }
}

// ---------------- K2: GEMM1 (selfz+zc), branch-free per-wave tile split
__global__ __launch_bounds__(256) void k2_gemm1(const void* __restrict__ feat,
                                                const __hip_bfloat16* __restrict__ featb,
                                                const __hip_bfloat16* __restrict__ Wpack,
                                                __hip_bfloat16* __restrict__ selfz,
                                                __hip_bfloat16* __restrict__ zc,
                                                const int* __restrict__ flags) {
    const int f32 = flags[0];
    const __hip_bfloat16* A = f32 ? featb : (const __hip_bfloat16*)feat;
    const int tid = threadIdx.x;
    const int wave = tid >> 6, lane = tid & 63;
    const int quad = lane >> 4, col = lane & 15;
    const int r0 = blockIdx.x * 16;
    int am = r0 + col;
    if (am >= N_NODES) am = N_NODES - 1;

    short8 a0 = *(const short8*)(A + am * F + quad * 8);
    short8 a1 = *(const short8*)(A + am * F + 32 + quad * 8);

    const short8* Wp = (const short8*)Wpack;
#pragma unroll
    for (int tt = 0; tt < 5; ++tt) {
        const int t = wave * 5 + tt;
        short8 b0 = Wp[(t * 2 + 0) * 64 + lane];
        short8 b1 = Wp[(t * 2 + 1) * 64 + lane];
        float4v acc = {0.f, 0.f, 0.f, 0.f};
        acc = __builtin_amdgcn_mfma_f32_16x16x32_bf16(a0, b0, acc, 0, 0, 0);
        acc = __builtin_amdgcn_mfma_f32_16x16x32_bf16(a1, b1, acc, 0, 0, 0);
        const int cb = t * 16 + col;
#pragma unroll
        for (int j = 0; j < 4; ++j)
            selfz[(r0 + quad * 4 + j) * HF + cb] = __float2bfloat16(acc[j]);
    }
    {
        const int t = 20 + wave;
        short8 b0 = Wp[(t * 2 + 0) * 64 + lane];
        short8 b1 = Wp[(t * 2 + 1) * 64 + lane];
        float4v acc = {0.f, 0.f, 0.f, 0.f};
        acc = __builtin_amdgcn_mfma_f32_16x16x32_bf16(a0, b0, acc, 0, 0, 0);
        acc = __builtin_amdgcn_mfma_f32_16x16x32_bf16(a1, b1, acc, 0, 0, 0);
        const int cb = wave * 16 + col;
#pragma unroll
        for (int j = 0; j < 4; ++j)
            zc[(r0 + quad * 4 + j) * F + cb] = __float2bfloat16(acc[j]);
    }
}

// ---------------- K2b: single-block scan, LDS-staged (coalesced global I/O)
#define SCAN_PAD 25600    // 1024*25
__global__ __launch_bounds__(1024) void k_scan(const int* __restrict__ deg,
                                               int* __restrict__ rowptr,
                                               int* __restrict__ cursor) {
    __shared__ int sdeg[SCAN_PAD];    // 102.4 KB
    __shared__ int tot[1024];         // + 4 KB = 106.4 KB < 160 KB
    const int t = threadIdx.x;

    for (int i = t; i < N_NODES; i += 1024) sdeg[i] = deg[i];
    for (int i = N_NODES + t; i < SCAN_PAD; i += 1024) sdeg[i] = 0;
    __syncthreads();

    // exclusive scan of this thread's 25-element chunk, in LDS
    const int base = t * 25;
    int s = 0;
#pragma unroll
    for (int i = 0; i < 25; ++i) {
        int v = sdeg[base + i];
        sdeg[base + i] = s;
        s += v;
    }
    tot[t] = s;
    __syncthreads();

    for (int off = 1; off < 1024; off <<= 1) {
        int v = (t >= off) ? tot[t - off] : 0;
        __syncthreads();
        tot[t] += v;
        __syncthreads();
    }

    const int chunk_off = (t > 0) ? tot[t - 1] : 0;
#pragma unroll
    for (int i = 0; i < 25; ++i) sdeg[base + i] += chunk_off;
    __syncthreads();

    for (int i = t; i < N_NODES; i += 1024) {
        int v = sdeg[i];
        rowptr[i] = v;
        cursor[i] = v;
    }
    if (t == 1023) rowptr[N_NODES] = tot[1023];
}

// ---------------- K3: blocks 0..1562 GEMM2 (a_src/a_dst); blocks 1563.. scatter
__global__ __launch_bounds__(256) void k3_gemm2(const __hip_bfloat16* __restrict__ zc,
                                                const __hip_bfloat16* __restrict__ W2pack,
                                                __hip_bfloat16* __restrict__ a_src,
                                                __hip_bfloat16* __restrict__ a_dst,
                                                const void* __restrict__ src,
                                                const void* __restrict__ dst,
                                                const void* __restrict__ et,
                                                int* __restrict__ cursor,
                                                unsigned* __restrict__ perm,
                                                const int* __restrict__ flags) {
    const int tid = threadIdx.x;
    if (blockIdx.x >= 1563) {               // ---- scatter blocks
        const int i64 = flags[1];
        const int e = (blockIdx.x - 1563) * 256 + tid;
        if (e >= N_EDGES) return;
        int d = ldi(dst, i64, e);
        int s = ldi(src, i64, e);
        int r = ldi(et, i64, e);
        int pos = atomicAdd(&cursor[d], 1);
        perm[pos] = ((unsigned)r << 16) | (unsigned)s;
        return;
    }
    const int wave = tid >> 6, lane = tid & 63;
    const int quad = lane >> 4, col = lane & 15;
    const int r0 = blockIdx.x * 16;
    const int am = r0 + col;

    short8 a0 = *(const short8*)(zc + am * F + quad * 8);
    short8 a1 = *(const short8*)(zc + am * F + 32 + quad * 8);

    const short8* Wp = (const short8*)W2pack;
#pragma unroll
    for (int tt = 0; tt < 5; ++tt) {
        const int t = wave * 5 + tt;
        short8 b0 = Wp[(t * 2 + 0) * 64 + lane];
        short8 b1 = Wp[(t * 2 + 1) * 64 + lane];
        float4v acc = {0.f, 0.f, 0.f, 0.f};
        acc = __builtin_amdgcn_mfma_f32_16x16x32_bf16(a0, b0, acc, 0, 0, 0);
        acc = __builtin_amdgcn_mfma_f32_16x16x32_bf16(a1, b1, acc, 0, 0, 0);
        const int cb = t * 16 + col;
        const int r = cb >> 4, part = (cb >> 3) & 1, h = cb & 7;
        __hip_bfloat16* dsta = part ? a_dst : a_src;
#pragma unroll
        for (int j = 0; j < 4; ++j)
            dsta[(r0 + quad * 4 + j) * 160 + r * 8 + h] = __float2bfloat16(acc[j]);
    }
}

// ---------------- K4: one wave per dst — logits add + leaky + weighted sum
__global__ __launch_bounds__(256) void k4_agg(const __hip_bfloat16* __restrict__ selfz,
                                              const unsigned short* __restrict__ zc,
                                              const __hip_bfloat16* __restrict__ a_src,
                                              const __hip_bfloat16* __restrict__ a_dst,
                                              const int* __restrict__ rowptr,
                                              const unsigned* __restrict__ perm,
                                              void* __restrict__ out,
                                              const int* __restrict__ flags) {
    __shared__ short sdv[4][160];
    const int f32 = flags[0];
    const int tid = threadIdx.x;
    const int wid = tid >> 6, lane = tid & 63;
    const int d = blockIdx.x * 4 + wid;       // 6250*4 = 25000

    if (lane < 20)
        *(short8*)&sdv[wid][lane * 8] = *(const short8*)((const short*)a_dst + d * 160 + lane * 8);
    __syncthreads();

    const int beg = rowptr[d], end = rowptr[d + 1];
    const short* as = (const short*)a_src;

    float acc[H] = {0.f, 0.f, 0.f, 0.f, 0.f};
    int e = beg;
    for (; e + 1 < end; e += 2) {
        const unsigned pk0 = perm[e], pk1 = perm[e + 1];
        const int s0 = (int)(pk0 & 0xFFFFu), r0 = (int)(pk0 >> 16);
        const int s1 = (int)(pk1 & 0xFFFFu), r1 = (int)(pk1 >> 16);
        short8 sv0 = *(const short8*)(as + s0 * 160 + r0 * 8);
        short8 sv1 = *(const short8*)(as + s1 * 160 + r1 * 8);
        const float zs0 = b2f(zc[s0 * F + lane]);
        const float zs1 = b2f(zc[s1 * F + lane]);
        short8 dv0 = *(const short8*)&sdv[wid][r0 * 8];
        short8 dv1 = *(const short8*)&sdv[wid][r1 * 8];
#pragma unroll
        for (int h = 0; h < H; ++h) {
            float t0 = b2f((unsigned short)sv0[h]) + b2f((unsigned short)dv0[h]);
            float t1 = b2f((unsigned short)sv1[h]) + b2f((unsigned short)dv1[h]);
            acc[h] += fmaxf(t0, 0.01f * t0) * zs0;
            acc[h] += fmaxf(t1, 0.01f * t1) * zs1;
        }
    }
    for (; e < end; ++e) {
        const unsigned pk = perm[e];
        const int s = (int)(pk & 0xFFFFu), r = (int)(pk >> 16);
        short8 sv = *(const short8*)(as + s * 160 + r * 8);
        const float zs = b2f(zc[s * F + lane]);
        short8 dv = *(const short8*)&sdv[wid][r * 8];
#pragma unroll
        for (int h = 0; h < H; ++h) {
            float t = b2f((unsigned short)sv[h]) + b2f((unsigned short)dv[h]);
            acc[h] += fmaxf(t, 0.01f * t) * zs;
        }
    }

    const int ob = d * HF + lane;
    if (f32) {
        float* o = (float*)out;
#pragma unroll
        for (int h = 0; h < H; ++h)
            o[ob + h * F] = acc[h] + __bfloat162float(selfz[ob + h * F]);
    } else {
        __hip_bfloat16* o = (__hip_bfloat16*)out;
#pragma unroll
        for (int h = 0; h < H; ++h)
            o[ob + h * F] = __float2bfloat16(acc[h] + __bfloat162float(selfz[ob + h * F]));
    }
}

extern "C" void kernel_launch(void* const* d_in, const int* in_sizes, int n_in,
                              void* d_out, int out_size, void* d_ws, size_t ws_size,
                              hipStream_t stream) {
    const void* feat = d_in[0];
    const void* src  = d_in[1];
    const void* dst  = d_in[2];
    const void* et   = d_in[3];
    const void* fcw  = d_in[4];
    const void* sfw  = d_in[5];
    const void* aw   = d_in[6];
    const void* wc   = d_in[7];

    // ws (~36.9 MB): selfz | zc | a_src | a_dst(alias featb) | Wpack | W2pack | perm | deg | cursor | rowptr | flags
    char* w = (char*)d_ws;
    __hip_bfloat16* selfz  = (__hip_bfloat16*)w;  w += (size_t)MPAD * HF * 2;    // 16.0 MB
    __hip_bfloat16* zc     = (__hip_bfloat16*)w;  w += (size_t)MPAD * F * 2;     // 3.2 MB
    __hip_bfloat16* a_src  = (__hip_bfloat16*)w;  w += (size_t)MPAD * 160 * 2;   // 8.0 MB
    __hip_bfloat16* a_dst  = (__hip_bfloat16*)w;  w += (size_t)MPAD * 160 * 2;   // 8.0 MB
    __hip_bfloat16* featb  = a_dst;  // featb dies (last read K2) before a_dst written (K3)
    __hip_bfloat16* Wpack  = (__hip_bfloat16*)w;  w += 24576 * 2;
    __hip_bfloat16* W2pack = (__hip_bfloat16*)w;  w += 20480 * 2;
    unsigned* perm = (unsigned*)w;                w += (size_t)N_EDGES * 4;
    int* deg       = (int*)w;                     w += (size_t)N_NODES * 4;
    int* cursor    = (int*)w;                     w += (size_t)N_NODES * 4;
    int* rowptr    = (int*)w;                     w += (size_t)(N_NODES + 1) * 4;
    int* flags     = (int*)w;

    k0_init<<<99, 256, 0, stream>>>((const unsigned int*)feat, (const unsigned int*)src, flags, deg);
    k1_setup<<<176 + 1250, 256, 0, stream>>>(feat, fcw, sfw, aw, wc, dst, Wpack, W2pack, featb, deg, flags);
    k2_gemm1<<<1563, 256, 0, stream>>>(feat, featb, Wpack, selfz, zc, flags);
    k_scan<<<1, 1024, 0, stream>>>(deg, rowptr, cursor);
    k3_gemm2<<<1563 + 1250, 256, 0, stream>>>(zc, W2pack, a_src, a_dst, src, dst, et, cursor, perm, flags);
    k4_agg<<<N_NODES / 4, 256, 0, stream>>>(selfz, (const unsigned short*)zc, a_src, a_dst, rowptr, perm, d_out, flags);
}

// Round 10
// 180.253 us; speedup vs baseline: 3.3003x; 1.0567x over previous
//
#include <hip/hip_runtime.h>
#include <hip/hip_bf16.h>

#define N_NODES 25000
#define N_EDGES 320000
#define F 64
#define H 5
#define R 20
#define B 10
#define HF 320            // H*F
#define MPAD 25008        // 1563*16 rows

typedef __attribute__((ext_vector_type(8))) short short8;
typedef __attribute__((ext_vector_type(4))) float float4v;

__device__ __forceinline__ float ldf(const void* p, int f32, int i) {
    if (f32) return ((const float*)p)[i];
    else     return __bfloat162float(((const __hip_bfloat16*)p)[i]);
}
__device__ __forceinline__ int ldi(const void* p, int i64, int i) {
    if (i64) return ((const int*)p)[2 * i];
    else     return ((const int*)p)[i];
}
__device__ __forceinline__ float b2f(unsigned short u) {
    union { unsigned u32; float f; } v; v.u32 = ((unsigned)u) << 16; return v.f;
}

// ---------------- K0: blocks 0..97 zero deg; block 98 probes dtypes
__global__ void k0_init(const unsigned int* __restrict__ feat_raw,
                        const unsigned int* __restrict__ src_raw,
                        int* __restrict__ flags, int* __restrict__ deg) {
    const int b = blockIdx.x, tid = threadIdx.x;
    if (b < 98) {
        int i = b * 256 + tid;
        if (i < N_NODES) deg[i] = 0;
        return;
    }
    __shared__ int sSane, sZero;
    if (tid == 0) { sSane = 0; sZero = 0; }
    __syncthreads();
    int sane = 0, zero = 0;
    for (int i = tid; i < 4096; i += 256) {
        unsigned w = feat_raw[i];
        unsigned e = (w >> 7) & 0xFF;
        if (e >= 110 && e <= 140) sane++;
        if (src_raw[2 * i + 1] == 0) zero++;
    }
    atomicAdd(&sSane, sane);
    atomicAdd(&sZero, zero);
    __syncthreads();
    if (tid == 0) {
        flags[0] = (sSane < 2048) ? 1 : 0;
        flags[1] = (sZero > 2048) ? 1 : 0;
    }
}

// ---------------- K1: blocks 0..175 pack weights; blocks 176.. hist + featb cvt
__global__ void k1_setup(const void* __restrict__ feat, const void* __restrict__ fcw,
                         const void* __restrict__ sfw, const void* __restrict__ aw,
                         const void* __restrict__ wc, const void* __restrict__ dst,
                         __hip_bfloat16* __restrict__ Wpack,
                         __hip_bfloat16* __restrict__ W2pack,
                         __hip_bfloat16* __restrict__ featb,
                         int* __restrict__ deg, const int* __restrict__ flags) {
    const int f32 = flags[0], i64 = flags[1];
    const int b = blockIdx.x, tid = threadIdx.x;
    if (b < 176) {
        const int idx = b * 256 + tid;
        if (idx < 24576) {
            int j = idx & 7, lane = (idx >> 3) & 63, fq = idx >> 9;
            int q = fq & 1, t = fq >> 1;
            int k = (q ? 32 : 0) + ((lane >> 4) << 3) + j;
            int c = t * 16 + (lane & 15);
            float v = (c < HF) ? ldf(sfw, f32, k * HF + c) : ldf(fcw, f32, k * F + (c - HF));
            Wpack[idx] = __float2bfloat16(v);
        } else if (idx < 24576 + 20480) {
            int id2 = idx - 24576;
            int j = id2 & 7, lane = (id2 >> 3) & 63, fq = id2 >> 9;
            int q = fq & 1, t = fq >> 1;
            int k = (q ? 32 : 0) + ((lane >> 4) << 3) + j;
            int c = t * 16 + (lane & 15);
            int r = c >> 4, part = (c >> 3) & 1, h = c & 7;
            float acc = 0.f;
            if (h < H) {
#pragma unroll
                for (int bb = 0; bb < B; ++bb)
                    acc += ldf(wc, f32, r * B + bb) *
                           ldf(aw, f32, bb * (2 * F * H) + (part * F + k) * H + h);
            }
            W2pack[id2] = __float2bfloat16(acc);
        }
    } else {
        const int e = (b - 176) * 256 + tid;
        if (e < N_EDGES) atomicAdd(&deg[ldi(dst, i64, e)], 1);
        if (f32) {
            for (int i = e; i < N_NODES * F; i += 1250 * 256)
                featb[i] = __float2bfloat16(((const float*)feat)[i]);
        }
    }
}

// ---------------- K2: fused GEMM1 (selfz + zc) and GEMM2 (a_src/a_dst via LDS zc)
__global__ __launch_bounds__(256) void k2_gemm(const void* __restrict__ feat,
                                               const __hip_bfloat16* __restrict__ featb,
                                               const __hip_bfloat16* __restrict__ Wpack,
                                               const __hip_bfloat16* __restrict__ W2pack,
                                               __hip_bfloat16* __restrict__ selfz,
                                               __hip_bfloat16* __restrict__ zc,
                                               __hip_bfloat16* __restrict__ a_src,
                                               __hip_bfloat16* __restrict__ a_dst,
                                               const int* __restrict__ flags) {
    __shared__ short zl[16][66];   // 16 rows of zc tile, +2 pad breaks bank stride
    const int f32 = flags[0];
    const __hip_bfloat16* A = f32 ? featb : (const __hip_bfloat16*)feat;
    const int tid = threadIdx.x;
    const int wave = tid >> 6, lane = tid & 63;
    const int quad = lane >> 4, col = lane & 15;
    const int r0 = blockIdx.x * 16;
    int am = r0 + col;
    if (am >= N_NODES) am = N_NODES - 1;

    short8 a0 = *(const short8*)(A + am * F + quad * 8);
    short8 a1 = *(const short8*)(A + am * F + 32 + quad * 8);

    const short8* Wp = (const short8*)Wpack;

    // ---- zc tile (t = 20 + wave), store to global AND stage into LDS
    {
        const int t = 20 + wave;
        short8 b0 = Wp[(t * 2 + 0) * 64 + lane];
        short8 b1 = Wp[(t * 2 + 1) * 64 + lane];
        float4v acc = {0.f, 0.f, 0.f, 0.f};
        acc = __builtin_amdgcn_mfma_f32_16x16x32_bf16(a0, b0, acc, 0, 0, 0);
        acc = __builtin_amdgcn_mfma_f32_16x16x32_bf16(a1, b1, acc, 0, 0, 0);
        const int cb = wave * 16 + col;
#pragma unroll
        for (int j = 0; j < 4; ++j) {
            __hip_bfloat16 v = __float2bfloat16(acc[j]);
            zc[(r0 + quad * 4 + j) * F + cb] = v;
            zl[quad * 4 + j][cb] = *(short*)&v;
        }
    }
    __syncthreads();

    // ---- GEMM2 A-fragments from LDS (A2[m][k] = zc row m=lane&15, k=quad*8+j)
    short8 c0 = *(const short8*)&zl[col][quad * 8];
    short8 c1 = *(const short8*)&zl[col][32 + quad * 8];

    // ---- selfz tiles (t = wave*5 .. +4)
#pragma unroll
    for (int tt = 0; tt < 5; ++tt) {
        const int t = wave * 5 + tt;
        short8 b0 = Wp[(t * 2 + 0) * 64 + lane];
        short8 b1 = Wp[(t * 2 + 1) * 64 + lane];
        float4v acc = {0.f, 0.f, 0.f, 0.f};
        acc = __builtin_amdgcn_mfma_f32_16x16x32_bf16(a0, b0, acc, 0, 0, 0);
        acc = __builtin_amdgcn_mfma_f32_16x16x32_bf16(a1, b1, acc, 0, 0, 0);
        const int cb = t * 16 + col;
#pragma unroll
        for (int j = 0; j < 4; ++j)
            selfz[(r0 + quad * 4 + j) * HF + cb] = __float2bfloat16(acc[j]);
    }

    // ---- GEMM2 tiles (t = wave*5 .. +4, covers 0..19) -> a_src/a_dst
    const short8* W2p = (const short8*)W2pack;
#pragma unroll
    for (int tt = 0; tt < 5; ++tt) {
        const int t = wave * 5 + tt;
        short8 b0 = W2p[(t * 2 + 0) * 64 + lane];
        short8 b1 = W2p[(t * 2 + 1) * 64 + lane];
        float4v acc = {0.f, 0.f, 0.f, 0.f};
        acc = __builtin_amdgcn_mfma_f32_16x16x32_bf16(c0, b0, acc, 0, 0, 0);
        acc = __builtin_amdgcn_mfma_f32_16x16x32_bf16(c1, b1, acc, 0, 0, 0);
        const int cb = t * 16 + col;
        const int r = cb >> 4, part = (cb >> 3) & 1, h = cb & 7;
        __hip_bfloat16* dsta = part ? a_dst : a_src;
#pragma unroll
        for (int j = 0; j < 4; ++j)
            dsta[(r0 + quad * 4 + j) * 160 + r * 8 + h] = __float2bfloat16(acc[j]);
    }
}

// ---------------- K2b: single-block scan, LDS-staged (coalesced global I/O)
#define SCAN_PAD 25600    // 1024*25
__global__ __launch_bounds__(1024) void k_scan(const int* __restrict__ deg,
                                               int* __restrict__ rowptr,
                                               int* __restrict__ cursor) {
    __shared__ int sdeg[SCAN_PAD];
    __shared__ int tot[1024];
    const int t = threadIdx.x;

    for (int i = t; i < N_NODES; i += 1024) sdeg[i] = deg[i];
    for (int i = N_NODES + t; i < SCAN_PAD; i += 1024) sdeg[i] = 0;
    __syncthreads();

    const int base = t * 25;
    int s = 0;
#pragma unroll
    for (int i = 0; i < 25; ++i) {
        int v = sdeg[base + i];
        sdeg[base + i] = s;
        s += v;
    }
    tot[t] = s;
    __syncthreads();

    for (int off = 1; off < 1024; off <<= 1) {
        int v = (t >= off) ? tot[t - off] : 0;
        __syncthreads();
        tot[t] += v;
        __syncthreads();
    }

    const int chunk_off = (t > 0) ? tot[t - 1] : 0;
#pragma unroll
    for (int i = 0; i < 25; ++i) sdeg[base + i] += chunk_off;
    __syncthreads();

    for (int i = t; i < N_NODES; i += 1024) {
        int v = sdeg[i];
        rowptr[i] = v;
        cursor[i] = v;
    }
    if (t == 1023) rowptr[N_NODES] = tot[1023];
}

// ---------------- K3: scatter edges into CSR order, packed (rel<<16)|src
__global__ void k3_scatter(const void* __restrict__ src, const void* __restrict__ dst,
                           const void* __restrict__ et, int* __restrict__ cursor,
                           unsigned* __restrict__ perm, const int* __restrict__ flags,
                           int ne) {
    const int i64 = flags[1];
    int e = blockIdx.x * blockDim.x + threadIdx.x;
    if (e >= ne) return;
    int d = ldi(dst, i64, e);
    int s = ldi(src, i64, e);
    int r = ldi(et, i64, e);
    int pos = atomicAdd(&cursor[d], 1);
    perm[pos] = ((unsigned)r << 16) | (unsigned)s;
}

// ---------------- K4: one wave per dst — 4-deep unrolled gather + aggregate
__global__ __launch_bounds__(256) void k4_agg(const __hip_bfloat16* __restrict__ selfz,
                                              const unsigned short* __restrict__ zc,
                                              const __hip_bfloat16* __restrict__ a_src,
                                              const __hip_bfloat16* __restrict__ a_dst,
                                              const int* __restrict__ rowptr,
                                              const unsigned* __restrict__ perm,
                                              void* __restrict__ out,
                                              const int* __restrict__ flags) {
    __shared__ short sdv[4][160];
    const int f32 = flags[0];
    const int tid = threadIdx.x;
    const int wid = tid >> 6, lane = tid & 63;
    const int d = blockIdx.x * 4 + wid;       // 6250*4 = 25000

    if (lane < 20)
        *(short8*)&sdv[wid][lane * 8] = *(const short8*)((const short*)a_dst + d * 160 + lane * 8);
    __syncthreads();

    const int beg = rowptr[d], end = rowptr[d + 1];
    const short* as = (const short*)a_src;

    float acc[H] = {0.f, 0.f, 0.f, 0.f, 0.f};
    int e = beg;
    for (; e + 4 <= end; e += 4) {
        unsigned pk[4];
        int s_[4], r_[4];
#pragma unroll
        for (int u = 0; u < 4; ++u) pk[u] = perm[e + u];
#pragma unroll
        for (int u = 0; u < 4; ++u) { s_[u] = (int)(pk[u] & 0xFFFFu); r_[u] = (int)(pk[u] >> 16); }
        short8 sv[4];
        float zs[4];
#pragma unroll
        for (int u = 0; u < 4; ++u) sv[u] = *(const short8*)(as + s_[u] * 160 + r_[u] * 8);
#pragma unroll
        for (int u = 0; u < 4; ++u) zs[u] = b2f(zc[s_[u] * F + lane]);
        short8 dv[4];
#pragma unroll
        for (int u = 0; u < 4; ++u) dv[u] = *(const short8*)&sdv[wid][r_[u] * 8];
#pragma unroll
        for (int u = 0; u < 4; ++u) {
#pragma unroll
            for (int h = 0; h < H; ++h) {
                float t = b2f((unsigned short)sv[u][h]) + b2f((unsigned short)dv[u][h]);
                acc[h] += fmaxf(t, 0.01f * t) * zs[u];
            }
        }
    }
    for (; e < end; ++e) {
        const unsigned pk = perm[e];
        const int s = (int)(pk & 0xFFFFu), r = (int)(pk >> 16);
        short8 sv = *(const short8*)(as + s * 160 + r * 8);
        const float zs = b2f(zc[s * F + lane]);
        short8 dv = *(const short8*)&sdv[wid][r * 8];
#pragma unroll
        for (int h = 0; h < H; ++h) {
            float t = b2f((unsigned short)sv[h]) + b2f((unsigned short)dv[h]);
            acc[h] += fmaxf(t, 0.01f * t) * zs;
        }
    }

    const int ob = d * HF + lane;
    if (f32) {
        float* o = (float*)out;
#pragma unroll
        for (int h = 0; h < H; ++h)
            o[ob + h * F] = acc[h] + __bfloat162float(selfz[ob + h * F]);
    } else {
        __hip_bfloat16* o = (__hip_bfloat16*)out;
#pragma unroll
        for (int h = 0; h < H; ++h)
            o[ob + h * F] = __float2bfloat16(acc[h] + __bfloat162float(selfz[ob + h * F]));
    }
}

extern "C" void kernel_launch(void* const* d_in, const int* in_sizes, int n_in,
                              void* d_out, int out_size, void* d_ws, size_t ws_size,
                              hipStream_t stream) {
    const void* feat = d_in[0];
    const void* src  = d_in[1];
    const void* dst  = d_in[2];
    const void* et   = d_in[3];
    const void* fcw  = d_in[4];
    const void* sfw  = d_in[5];
    const void* aw   = d_in[6];
    const void* wc   = d_in[7];

    // ws (~40.1 MB): selfz | zc | a_src | a_dst | featb | Wpack | W2pack | perm | deg | cursor | rowptr | flags
    char* w = (char*)d_ws;
    __hip_bfloat16* selfz  = (__hip_bfloat16*)w;  w += (size_t)MPAD * HF * 2;    // 16.0 MB
    __hip_bfloat16* zc     = (__hip_bfloat16*)w;  w += (size_t)MPAD * F * 2;     // 3.2 MB
    __hip_bfloat16* a_src  = (__hip_bfloat16*)w;  w += (size_t)MPAD * 160 * 2;   // 8.0 MB
    __hip_bfloat16* a_dst  = (__hip_bfloat16*)w;  w += (size_t)MPAD * 160 * 2;   // 8.0 MB
    __hip_bfloat16* featb  = (__hip_bfloat16*)w;  w += (size_t)N_NODES * F * 2;  // 3.2 MB (own region: no alias)
    __hip_bfloat16* Wpack  = (__hip_bfloat16*)w;  w += 24576 * 2;
    __hip_bfloat16* W2pack = (__hip_bfloat16*)w;  w += 20480 * 2;
    unsigned* perm = (unsigned*)w;                w += (size_t)N_EDGES * 4;
    int* deg       = (int*)w;                     w += (size_t)N_NODES * 4;
    int* cursor    = (int*)w;                     w += (size_t)N_NODES * 4;
    int* rowptr    = (int*)w;                     w += (size_t)(N_NODES + 1) * 4;
    int* flags     = (int*)w;

    k0_init<<<99, 256, 0, stream>>>((const unsigned int*)feat, (const unsigned int*)src, flags, deg);
    k1_setup<<<176 + 1250, 256, 0, stream>>>(feat, fcw, sfw, aw, wc, dst, Wpack, W2pack, featb, deg, flags);
    k2_gemm<<<1563, 256, 0, stream>>>(feat, featb, Wpack, W2pack, selfz, zc, a_src, a_dst, flags);
    k_scan<<<1, 1024, 0, stream>>>(deg, rowptr, cursor);
    k3_scatter<<<(N_EDGES + 255) / 256, 256, 0, stream>>>(src, dst, et, cursor, perm, flags, N_EDGES);
    k4_agg<<<N_NODES / 4, 256, 0, stream>>>(selfz, (const unsigned short*)zc, a_src, a_dst, rowptr, perm, d_out, flags);
}

// Round 11
// 179.451 us; speedup vs baseline: 3.3150x; 1.0045x over previous
//
#include <hip/hip_runtime.h>
#include <hip/hip_bf16.h>

#define N_NODES 25000
#define N_EDGES 320000
#define F 64
#define H 5
#define R 20
#define B 10
#define HF 320            // H*F
#define MPAD 25008        // 1563*16 rows

typedef __attribute__((ext_vector_type(8))) short short8;
typedef __attribute__((ext_vector_type(4))) short short4v;
typedef __attribute__((ext_vector_type(4))) float float4v;

__device__ __forceinline__ float ldf(const void* p, int f32, int i) {
    if (f32) return ((const float*)p)[i];
    else     return __bfloat162float(((const __hip_bfloat16*)p)[i]);
}
__device__ __forceinline__ int ldi(const void* p, int i64, int i) {
    if (i64) return ((const int*)p)[2 * i];
    else     return ((const int*)p)[i];
}
__device__ __forceinline__ float b2f(unsigned short u) {
    union { unsigned u32; float f; } v; v.u32 = ((unsigned)u) << 16; return v.f;
}
__device__ __forceinline__ short f2bs(float x) {
    __hip_bfloat16 v = __float2bfloat16(x); return *(short*)&v;
}

// ---- inline dtype probes (wave-uniform; call at kernel top, all lanes active)
__device__ __forceinline__ int probe_f32(const void* feat_raw) {
    unsigned w = ((const unsigned*)feat_raw)[threadIdx.x & 63];
    unsigned e = (w >> 7) & 0xFF;                    // bf16 exponent of low half
    unsigned long long m = __ballot(e >= 110 && e <= 140);
    return __popcll(m) < 32;                         // scattered exponents => fp32
}
__device__ __forceinline__ int probe_i64(const void* src_raw) {
    unsigned v = ((const unsigned*)src_raw)[2 * (threadIdx.x & 63) + 1];
    unsigned long long m = __ballot(v == 0);
    return __popcll(m) > 32;                         // odd words all zero => int64
}

// ---------------- K1: blocks 0..175 pack weights; blocks 176.. hist + featb cvt
__global__ void k1_setup(const void* __restrict__ feat, const void* __restrict__ src,
                         const void* __restrict__ fcw, const void* __restrict__ sfw,
                         const void* __restrict__ aw, const void* __restrict__ wc,
                         const void* __restrict__ dst,
                         __hip_bfloat16* __restrict__ Wpack,
                         __hip_bfloat16* __restrict__ W2pack,
                         __hip_bfloat16* __restrict__ featb,
                         int* __restrict__ deg) {
    const int f32 = probe_f32(feat);
    const int i64 = probe_i64(src);
    const int b = blockIdx.x, tid = threadIdx.x;
    if (b < 176) {
        const int idx = b * 256 + tid;
        if (idx < 24576) {
            int j = idx & 7, lane = (idx >> 3) & 63, fq = idx >> 9;
            int q = fq & 1, t = fq >> 1;
            int k = (q ? 32 : 0) + ((lane >> 4) << 3) + j;
            int c = t * 16 + (lane & 15);
            float v = (c < HF) ? ldf(sfw, f32, k * HF + c) : ldf(fcw, f32, k * F + (c - HF));
            Wpack[idx] = __float2bfloat16(v);
        } else if (idx < 24576 + 20480) {
            int id2 = idx - 24576;
            int j = id2 & 7, lane = (id2 >> 3) & 63, fq = id2 >> 9;
            int q = fq & 1, t = fq >> 1;
            int k = (q ? 32 : 0) + ((lane >> 4) << 3) + j;
            int c = t * 16 + (lane & 15);
            int r = c >> 4, part = (c >> 3) & 1, h = c & 7;
            float acc = 0.f;
            if (h < H) {
#pragma unroll
                for (int bb = 0; bb < B; ++bb)
                    acc += ldf(wc, f32, r * B + bb) *
                           ldf(aw, f32, bb * (2 * F * H) + (part * F + k) * H + h);
            }
            W2pack[id2] = __float2bfloat16(acc);
        }
    } else {
        const int e = (b - 176) * 256 + tid;
        if (e < N_EDGES) atomicAdd(&deg[ldi(dst, i64, e)], 1);
        if (f32) {
            for (int i = e; i < N_NODES * F; i += 1250 * 256)
                featb[i] = __float2bfloat16(((const float*)feat)[i]);
        }
    }
}

// ---------------- K2: fused GEMM1+GEMM2, transposed epilogues (packed 8B stores)
// Swapped mfma(b,a,acc): lane holds node row m = r0+(lane&15); the 4 acc regs
// are 4 CONSECUTIVE output cols n = t*16 + quad*4 + j  -> one short4 store.
__global__ __launch_bounds__(256) void k2_gemm(const void* __restrict__ feat,
                                               const __hip_bfloat16* __restrict__ featb,
                                               const __hip_bfloat16* __restrict__ Wpack,
                                               const __hip_bfloat16* __restrict__ W2pack,
                                               __hip_bfloat16* __restrict__ selfz,
                                               __hip_bfloat16* __restrict__ zc,
                                               __hip_bfloat16* __restrict__ a_src,
                                               __hip_bfloat16* __restrict__ a_dst) {
    __shared__ short zl[16][66];
    const int f32 = probe_f32(feat);
    const __hip_bfloat16* A = f32 ? featb : (const __hip_bfloat16*)feat;
    const int tid = threadIdx.x;
    const int wave = tid >> 6, lane = tid & 63;
    const int quad = lane >> 4, col = lane & 15;
    const int r0 = blockIdx.x * 16;
    int am = r0 + col;
    if (am >= N_NODES) am = N_NODES - 1;
    const int row = r0 + col;                 // output row this lane owns (clamped rows dup)

    short8 a0 = *(const short8*)(A + am * F + quad * 8);
    short8 a1 = *(const short8*)(A + am * F + 32 + quad * 8);

    const short8* Wp = (const short8*)Wpack;

    // ---- zc tile (t = 20 + wave): global + LDS stage, packed stores
    {
        const int t = 20 + wave;
        short8 b0 = Wp[(t * 2 + 0) * 64 + lane];
        short8 b1 = Wp[(t * 2 + 1) * 64 + lane];
        float4v acc = {0.f, 0.f, 0.f, 0.f};
        acc = __builtin_amdgcn_mfma_f32_16x16x32_bf16(b0, a0, acc, 0, 0, 0);
        acc = __builtin_amdgcn_mfma_f32_16x16x32_bf16(b1, a1, acc, 0, 0, 0);
        short4v pv;
#pragma unroll
        for (int j = 0; j < 4; ++j) pv[j] = f2bs(acc[j]);
        const int cb = wave * 16 + quad * 4;
        *(short4v*)(zc + row * F + cb) = pv;
        *(short4v*)&zl[col][cb] = pv;
    }
    __syncthreads();

    // ---- GEMM2 A-side (zc^T as 2nd operand): zl[m=col][k=quad*8+j]
    short8 c0 = *(const short8*)&zl[col][quad * 8];
    short8 c1 = *(const short8*)&zl[col][32 + quad * 8];

    // ---- selfz tiles (t = wave*5 .. +4)
#pragma unroll
    for (int tt = 0; tt < 5; ++tt) {
        const int t = wave * 5 + tt;
        short8 b0 = Wp[(t * 2 + 0) * 64 + lane];
        short8 b1 = Wp[(t * 2 + 1) * 64 + lane];
        float4v acc = {0.f, 0.f, 0.f, 0.f};
        acc = __builtin_amdgcn_mfma_f32_16x16x32_bf16(b0, a0, acc, 0, 0, 0);
        acc = __builtin_amdgcn_mfma_f32_16x16x32_bf16(b1, a1, acc, 0, 0, 0);
        short4v pv;
#pragma unroll
        for (int j = 0; j < 4; ++j) pv[j] = f2bs(acc[j]);
        *(short4v*)(selfz + row * HF + t * 16 + quad * 4) = pv;
    }

    // ---- GEMM2 tiles (t = wave*5 .. +4) -> a_src (quads 0,1) / a_dst (quads 2,3)
    const short8* W2p = (const short8*)W2pack;
    __hip_bfloat16* dsta = (quad & 2) ? a_dst : a_src;
    const int hoff = (quad & 1) * 4;
#pragma unroll
    for (int tt = 0; tt < 5; ++tt) {
        const int t = wave * 5 + tt;
        short8 b0 = W2p[(t * 2 + 0) * 64 + lane];
        short8 b1 = W2p[(t * 2 + 1) * 64 + lane];
        float4v acc = {0.f, 0.f, 0.f, 0.f};
        acc = __builtin_amdgcn_mfma_f32_16x16x32_bf16(b0, c0, acc, 0, 0, 0);
        acc = __builtin_amdgcn_mfma_f32_16x16x32_bf16(b1, c1, acc, 0, 0, 0);
        short4v pv;
#pragma unroll
        for (int j = 0; j < 4; ++j) pv[j] = f2bs(acc[j]);
        *(short4v*)(dsta + row * 160 + t * 8 + hoff) = pv;
    }
}

// ---------------- K2b: single-block scan, LDS-staged (coalesced global I/O)
#define SCAN_PAD 25600    // 1024*25
__global__ __launch_bounds__(1024) void k_scan(const int* __restrict__ deg,
                                               int* __restrict__ rowptr,
                                               int* __restrict__ cursor) {
    __shared__ int sdeg[SCAN_PAD];
    __shared__ int tot[1024];
    const int t = threadIdx.x;

    for (int i = t; i < N_NODES; i += 1024) sdeg[i] = deg[i];
    for (int i = N_NODES + t; i < SCAN_PAD; i += 1024) sdeg[i] = 0;
    __syncthreads();

    const int base = t * 25;
    int s = 0;
#pragma unroll
    for (int i = 0; i < 25; ++i) {
        int v = sdeg[base + i];
        sdeg[base + i] = s;
        s += v;
    }
    tot[t] = s;
    __syncthreads();

    for (int off = 1; off < 1024; off <<= 1) {
        int v = (t >= off) ? tot[t - off] : 0;
        __syncthreads();
        tot[t] += v;
        __syncthreads();
    }

    const int chunk_off = (t > 0) ? tot[t - 1] : 0;
#pragma unroll
    for (int i = 0; i < 25; ++i) sdeg[base + i] += chunk_off;
    __syncthreads();

    for (int i = t; i < N_NODES; i += 1024) {
        int v = sdeg[i];
        rowptr[i] = v;
        cursor[i] = v;
    }
    if (t == 1023) rowptr[N_NODES] = tot[1023];
}

// ---------------- K3: scatter edges into CSR order, packed (rel<<16)|src
__global__ void k3_scatter(const void* __restrict__ src, const void* __restrict__ dst,
                           const void* __restrict__ et, int* __restrict__ cursor,
                           unsigned* __restrict__ perm, int ne) {
    const int i64 = probe_i64(src);
    int e = blockIdx.x * blockDim.x + threadIdx.x;
    if (e >= ne) return;
    int d = ldi(dst, i64, e);
    int s = ldi(src, i64, e);
    int r = ldi(et, i64, e);
    int pos = atomicAdd(&cursor[d], 1);
    perm[pos] = ((unsigned)r << 16) | (unsigned)s;
}

// ---------------- K4: one wave per dst — 4-deep unrolled gather + aggregate
__global__ __launch_bounds__(256) void k4_agg(const void* __restrict__ feat_raw,
                                              const __hip_bfloat16* __restrict__ selfz,
                                              const unsigned short* __restrict__ zc,
                                              const __hip_bfloat16* __restrict__ a_src,
                                              const __hip_bfloat16* __restrict__ a_dst,
                                              const int* __restrict__ rowptr,
                                              const unsigned* __restrict__ perm,
                                              void* __restrict__ out) {
    __shared__ short sdv[4][160];
    const int f32 = probe_f32(feat_raw);
    const int tid = threadIdx.x;
    const int wid = tid >> 6, lane = tid & 63;
    const int d = blockIdx.x * 4 + wid;       // 6250*4 = 25000

    if (lane < 20)
        *(short8*)&sdv[wid][lane * 8] = *(const short8*)((const short*)a_dst + d * 160 + lane * 8);
    __syncthreads();

    const int beg = rowptr[d], end = rowptr[d + 1];
    const short* as = (const short*)a_src;

    float acc[H] = {0.f, 0.f, 0.f, 0.f, 0.f};
    int e = beg;
    for (; e + 4 <= end; e += 4) {
        unsigned pk[4];
        int s_[4], r_[4];
#pragma unroll
        for (int u = 0; u < 4; ++u) pk[u] = perm[e + u];
#pragma unroll
        for (int u = 0; u < 4; ++u) { s_[u] = (int)(pk[u] & 0xFFFFu); r_[u] = (int)(pk[u] >> 16); }
        short8 sv[4];
        float zs[4];
#pragma unroll
        for (int u = 0; u < 4; ++u) sv[u] = *(const short8*)(as + s_[u] * 160 + r_[u] * 8);
#pragma unroll
        for (int u = 0; u < 4; ++u) zs[u] = b2f(zc[s_[u] * F + lane]);
        short8 dv[4];
#pragma unroll
        for (int u = 0; u < 4; ++u) dv[u] = *(const short8*)&sdv[wid][r_[u] * 8];
#pragma unroll
        for (int u = 0; u < 4; ++u) {
#pragma unroll
            for (int h = 0; h < H; ++h) {
                float t = b2f((unsigned short)sv[u][h]) + b2f((unsigned short)dv[u][h]);
                acc[h] += fmaxf(t, 0.01f * t) * zs[u];
            }
        }
    }
    for (; e < end; ++e) {
        const unsigned pk = perm[e];
        const int s = (int)(pk & 0xFFFFu), r = (int)(pk >> 16);
        short8 sv = *(const short8*)(as + s * 160 + r * 8);
        const float zs = b2f(zc[s * F + lane]);
        short8 dv = *(const short8*)&sdv[wid][r * 8];
#pragma unroll
        for (int h = 0; h < H; ++h) {
            float t = b2f((unsigned short)sv[h]) + b2f((unsigned short)dv[h]);
            acc[h] += fmaxf(t, 0.01f * t) * zs;
        }
    }

    const int ob = d * HF + lane;
    if (f32) {
        float* o = (float*)out;
#pragma unroll
        for (int h = 0; h < H; ++h)
            o[ob + h * F] = acc[h] + __bfloat162float(selfz[ob + h * F]);
    } else {
        __hip_bfloat16* o = (__hip_bfloat16*)out;
#pragma unroll
        for (int h = 0; h < H; ++h)
            o[ob + h * F] = __float2bfloat16(acc[h] + __bfloat162float(selfz[ob + h * F]));
    }
}

extern "C" void kernel_launch(void* const* d_in, const int* in_sizes, int n_in,
                              void* d_out, int out_size, void* d_ws, size_t ws_size,
                              hipStream_t stream) {
    const void* feat = d_in[0];
    const void* src  = d_in[1];
    const void* dst  = d_in[2];
    const void* et   = d_in[3];
    const void* fcw  = d_in[4];
    const void* sfw  = d_in[5];
    const void* aw   = d_in[6];
    const void* wc   = d_in[7];

    // ws (~40 MB): selfz | zc | a_src | a_dst | featb | Wpack | W2pack | perm | deg | cursor | rowptr
    char* w = (char*)d_ws;
    __hip_bfloat16* selfz  = (__hip_bfloat16*)w;  w += (size_t)MPAD * HF * 2;
    __hip_bfloat16* zc     = (__hip_bfloat16*)w;  w += (size_t)MPAD * F * 2;
    __hip_bfloat16* a_src  = (__hip_bfloat16*)w;  w += (size_t)MPAD * 160 * 2;
    __hip_bfloat16* a_dst  = (__hip_bfloat16*)w;  w += (size_t)MPAD * 160 * 2;
    __hip_bfloat16* featb  = (__hip_bfloat16*)w;  w += (size_t)N_NODES * F * 2;
    __hip_bfloat16* Wpack  = (__hip_bfloat16*)w;  w += 24576 * 2;
    __hip_bfloat16* W2pack = (__hip_bfloat16*)w;  w += 20480 * 2;
    unsigned* perm = (unsigned*)w;                w += (size_t)N_EDGES * 4;
    int* deg       = (int*)w;                     w += (size_t)N_NODES * 4;
    int* cursor    = (int*)w;                     w += (size_t)N_NODES * 4;
    int* rowptr    = (int*)w;

    hipMemsetAsync(deg, 0, (size_t)N_NODES * 4, stream);
    k1_setup<<<176 + 1250, 256, 0, stream>>>(feat, src, fcw, sfw, aw, wc, dst,
                                             Wpack, W2pack, featb, deg);
    k2_gemm<<<1563, 256, 0, stream>>>(feat, featb, Wpack, W2pack, selfz, zc, a_src, a_dst);
    k_scan<<<1, 1024, 0, stream>>>(deg, rowptr, cursor);
    k3_scatter<<<(N_EDGES + 255) / 256, 256, 0, stream>>>(src, dst, et, cursor, perm, N_EDGES);
    k4_agg<<<N_NODES / 4, 256, 0, stream>>>(feat, selfz, (const unsigned short*)zc,
                                            a_src, a_dst, rowptr, perm, d_out);
}